// Round 4
// baseline (34231.039 us; speedup 1.0000x reference)
//
#include <hip/hip_runtime.h>
#include <stdint.h>

#define D_DIM 512
#define SPLIT_K 384     // OpenBLAS sgemm kc (Haswell/ZEN SGEMM_DEFAULT_Q)
#define DELTA 2.0e-3f   // screening window: > 2*err_max + 2*ULP(512), provably safe
#define MAXC 32         // candidate slots per row

typedef unsigned long long u64;
typedef float f32x4 __attribute__((ext_vector_type(4)));
typedef short s16x8 __attribute__((ext_vector_type(8)));

static __device__ inline unsigned short f2bf(float x) {  // RNE f32->bf16
  unsigned u = __float_as_uint(x);
  u = (u + 0x7FFFu + ((u >> 16) & 1u)) >> 16;
  return (unsigned short)u;
}
static __device__ inline unsigned mono(float f) {  // monotone float->uint
  unsigned u = __float_as_uint(f);
  return (u & 0x80000000u) ? ~u : (u | 0x80000000u);
}
static __device__ inline float unmono(unsigned m) {
  return __uint_as_float((m & 0x80000000u) ? (m & 0x7FFFFFFFu) : ~m);
}

// ---------------- init workspace (histogram only) ----------------
__global__ void k_init(int* __restrict__ counts, int K) {
  int i = blockIdx.x * blockDim.x + threadIdx.x;
  if (i < K) counts[i] = 0;
}

// ---------------- numpy-replicated row sum of squares (validated r2) ----------------
__global__ void k_rowsq(const float* __restrict__ X, float* __restrict__ out, int nrows) {
  int t = threadIdx.x;
  int row = blockIdx.x * 4 + (t >> 6);
  int l = t & 63;
  if (row >= nrows) return;
  int b = l >> 4;
  int L = l & 15;
  const float* p = X + (size_t)row * D_DIM + b * 128 + L;
  float v[8];
#pragma unroll
  for (int j = 0; j < 8; ++j) {
    float x = p[16 * j];
    float sq = x * x;
    asm volatile("" : "+v"(sq));  // numpy squares then sums: no fma contraction
    v[j] = sq;
  }
  float s = ((v[0] + v[1]) + (v[2] + v[3])) + ((v[4] + v[5]) + (v[6] + v[7]));
  s += __shfl_xor(s, 8, 64);
  s += __shfl_xor(s, 4, 64);
  s += __shfl_xor(s, 2, 64);
  s += __shfl_xor(s, 1, 64);
  s += __shfl_xor(s, 16, 64);
  s += __shfl_xor(s, 32, 64);
  if (l == 0) out[row] = s;
}

// ---------------- E f32 -> bf16 ----------------
__global__ void k_ebf(const float* __restrict__ E, unsigned short* __restrict__ Ebf, int n8) {
  int i = blockIdx.x * blockDim.x + threadIdx.x;
  if (i >= n8) return;
  const float4 f0 = ((const float4*)E)[i * 2];
  const float4 f1 = ((const float4*)E)[i * 2 + 1];
  s16x8 o;
  o[0] = (short)f2bf(f0.x); o[1] = (short)f2bf(f0.y);
  o[2] = (short)f2bf(f0.z); o[3] = (short)f2bf(f0.w);
  o[4] = (short)f2bf(f1.x); o[5] = (short)f2bf(f1.y);
  o[6] = (short)f2bf(f1.z); o[7] = (short)f2bf(f1.w);
  ((s16x8*)Ebf)[i] = o;
}

// ---------------- MFMA bf16 screening: per-row runmin + candidate collection ----------------
// Block: 512 thr (8 waves, 2M x 4N), owns 128 rows. A staged once in LDS (bf16,
// XOR-swizzled). E streamed bf16 global->VGPR as B-fragments. s~ = e2 - 2*dot.
__global__ __launch_bounds__(512) void k_screen(
    const float* __restrict__ A, const unsigned short* __restrict__ Ebf,
    const float* __restrict__ e2, int* __restrict__ cand_cnt,
    unsigned short* __restrict__ cand, int K) {
  __shared__ unsigned runmin[128];
  __shared__ unsigned cnt[128];
  __shared__ unsigned short list[128 * MAXC];
  __shared__ __align__(16) char Alds[128 * 1024];  // 128 rows x 512 bf16, swizzled

  const int t = threadIdx.x;
  const int m0 = blockIdx.x * 128;

  if (t < 128) { runmin[t] = 0xFFFFFFFFu; cnt[t] = 0; }

  // stage A -> bf16 LDS, 16B chunks, byte XOR-swizzle ((row&7)<<4)
  {
    int row = t >> 2;
    int s4 = t & 3;
    const float* ar = A + (size_t)(m0 + row) * D_DIM;
#pragma unroll
    for (int c = 0; c < 16; ++c) {
      int ch = s4 * 16 + c;  // 16B chunk = 8 bf16, d = ch*8
      float4 f0 = *(const float4*)(ar + ch * 8);
      float4 f1 = *(const float4*)(ar + ch * 8 + 4);
      s16x8 o;
      o[0] = (short)f2bf(f0.x); o[1] = (short)f2bf(f0.y);
      o[2] = (short)f2bf(f0.z); o[3] = (short)f2bf(f0.w);
      o[4] = (short)f2bf(f1.x); o[5] = (short)f2bf(f1.y);
      o[6] = (short)f2bf(f1.z); o[7] = (short)f2bf(f1.w);
      int off = ((row * 64 + ch) * 16) ^ ((row & 7) << 4);
      *(s16x8*)(Alds + off) = o;
    }
  }
  __syncthreads();

  const int lane = t & 63;
  const int wid = t >> 6;
  const int wm = wid >> 2;   // 0..1: rows wm*64..+63
  const int wn = wid & 3;    // 0..3: cols wn*32..+31
  const int l15 = lane & 15;
  const int lhi = lane >> 4; // 0..3

  for (int n0 = 0; n0 < K; n0 += 128) {
    f32x4 acc[4][2];
#pragma unroll
    for (int r = 0; r < 4; ++r)
#pragma unroll
      for (int c = 0; c < 2; ++c) acc[r][c] = (f32x4){0.f, 0.f, 0.f, 0.f};

    const unsigned short* B0 = Ebf + (size_t)(n0 + wn * 32 + l15) * D_DIM + lhi * 8;
    const unsigned short* B1 = B0 + 16 * D_DIM;
#pragma unroll
    for (int dk = 0; dk < 16; ++dk) {  // d0 = dk*32
      s16x8 b0 = *(const s16x8*)(B0 + dk * 32);
      s16x8 b1 = *(const s16x8*)(B1 + dk * 32);
      s16x8 af[4];
#pragma unroll
      for (int r = 0; r < 4; ++r) {
        int row = wm * 64 + r * 16 + l15;
        int off = ((row * 64 + dk * 4 + lhi) * 16) ^ ((row & 7) << 4);
        af[r] = *(const s16x8*)(Alds + off);
      }
#pragma unroll
      for (int r = 0; r < 4; ++r) {
        acc[r][0] = __builtin_amdgcn_mfma_f32_16x16x32_bf16(af[r], b0, acc[r][0], 0, 0, 0);
        acc[r][1] = __builtin_amdgcn_mfma_f32_16x16x32_bf16(af[r], b1, acc[r][1], 0, 0, 0);
      }
    }

    float e2c0 = e2[n0 + wn * 32 + l15];
    float e2c1 = e2[n0 + wn * 32 + 16 + l15];
    float s[4][2][4];
#pragma unroll
    for (int r = 0; r < 4; ++r)
#pragma unroll
      for (int g = 0; g < 4; ++g) {
        s[r][0][g] = fmaf(-2.f, acc[r][0][g], e2c0);
        s[r][1][g] = fmaf(-2.f, acc[r][1][g], e2c1);
      }
    // shared running-min per row (monotone-u32 domain)
#pragma unroll
    for (int r = 0; r < 4; ++r)
#pragma unroll
      for (int g = 0; g < 4; ++g) {
        float mn = fminf(s[r][0][g], s[r][1][g]);
        mn = fminf(mn, __shfl_xor(mn, 1, 64));
        mn = fminf(mn, __shfl_xor(mn, 2, 64));
        mn = fminf(mn, __shfl_xor(mn, 4, 64));
        mn = fminf(mn, __shfl_xor(mn, 8, 64));
        if (l15 == 0) atomicMin(&runmin[wm * 64 + r * 16 + lhi * 4 + g], mono(mn));
      }
    __syncthreads();
    // collect: any runmin >= final row-min keeps the superset guarantee
#pragma unroll
    for (int r = 0; r < 4; ++r)
#pragma unroll
      for (int g = 0; g < 4; ++g) {
        int row = wm * 64 + r * 16 + lhi * 4 + g;
        float thr = unmono(runmin[row]) + DELTA;
#pragma unroll
        for (int c = 0; c < 2; ++c)
          if (s[r][c][g] <= thr) {
            unsigned p = atomicAdd(&cnt[row], 1u);
            if (p < MAXC) list[row * MAXC + p] = (unsigned short)(n0 + wn * 32 + c * 16 + l15);
          }
      }
  }
  __syncthreads();
  {
    int row = t >> 2;
    unsigned c = cnt[row];
    if ((t & 3) == 0) cand_cnt[m0 + row] = (int)c;
    unsigned cc = c < MAXC ? c : MAXC;
    for (unsigned p = t & 3; p < cc; p += 4)
      cand[(size_t)(m0 + row) * MAXC + p] = list[row * MAXC + p];
  }
}

// ---------------- exact numpy-f32 rescore of candidates ----------------
static __device__ inline u64 exact_pack(const float* __restrict__ ar,
                                        const float* __restrict__ er,
                                        float a2r, float e2k, int k) {
  float acc1 = 0.f, acc2 = 0.f;
  for (int d = 0; d < SPLIT_K; d += 4) {
    float4 a = *(const float4*)(ar + d);
    float4 e = *(const float4*)(er + d);
    acc1 = fmaf(a.x, e.x, acc1); acc1 = fmaf(a.y, e.y, acc1);
    acc1 = fmaf(a.z, e.z, acc1); acc1 = fmaf(a.w, e.w, acc1);
  }
  for (int d = SPLIT_K; d < D_DIM; d += 4) {
    float4 a = *(const float4*)(ar + d);
    float4 e = *(const float4*)(er + d);
    acc2 = fmaf(a.x, e.x, acc2); acc2 = fmaf(a.y, e.y, acc2);
    acc2 = fmaf(a.z, e.z, acc2); acc2 = fmaf(a.w, e.w, acc2);
  }
  float M = acc1 + acc2;          // BLAS kc-split merge
  float S = a2r + e2k;            // fl(a2 + e2)
  float s = fmaf(-2.f, M, S);     // fl(S - 2M)
  return ((u64)mono(s) << 32) | (unsigned)k;
}

__global__ __launch_bounds__(256) void k_rescore(
    const float* __restrict__ A, const float* __restrict__ E,
    const float* __restrict__ a2, const float* __restrict__ e2,
    const int* __restrict__ cand_cnt, const unsigned short* __restrict__ cand,
    float* __restrict__ out_idx, int* __restrict__ idx_ws, int K) {
  int lane = threadIdx.x & 63;
  int r = blockIdx.x * 4 + (threadIdx.x >> 6);
  int c = cand_cnt[r];
  const float* ar = A + (size_t)r * D_DIM;
  float a2r = a2[r];
  u64 best = ~0ULL;
  if (c <= MAXC) {
    if (lane < c) {
      int k = cand[(size_t)r * MAXC + lane];
      best = exact_pack(ar, E + (size_t)k * D_DIM, a2r, e2[k], k);
    }
  } else {  // overflow fallback: exact scan of all K (deterministic)
    for (int k = lane; k < K; k += 64) {
      u64 p = exact_pack(ar, E + (size_t)k * D_DIM, a2r, e2[k], k);
      if (p < best) best = p;
    }
  }
#pragma unroll
  for (int m = 1; m < 64; m <<= 1) {
    u64 o = __shfl_xor(best, m, 64);
    if (o < best) best = o;
  }
  if (lane == 0) {
    int idx = (int)(unsigned)(best & 0xFFFFFFFFULL);
    out_idx[r] = (float)idx;
    idx_ws[r] = idx;
  }
}

// ---------------- validated round-3 f32 argmin (ws-size fallback) ----------------
#define KTILE(D0, ACC)                                                          \
  {                                                                             \
    int r = t >> 2;                                                             \
    int c4 = (t & 3) << 2;                                                      \
    float4 va = *(const float4*)(A + (size_t)(m0 + r) * D_DIM + (D0) + c4);     \
    As[c4 + 0][r] = va.x; As[c4 + 1][r] = va.y;                                 \
    As[c4 + 2][r] = va.z; As[c4 + 3][r] = va.w;                                 \
    float4 vb = *(const float4*)(E + (size_t)(n0 + r) * D_DIM + (D0) + c4);     \
    Es[c4 + 0][r] = vb.x; Es[c4 + 1][r] = vb.y;                                 \
    Es[c4 + 2][r] = vb.z; Es[c4 + 3][r] = vb.w;                                 \
    __syncthreads();                                                            \
    _Pragma("unroll")                                                           \
    for (int dd = 0; dd < 16; ++dd) {                                           \
      float af[4], bf[8];                                                       \
      *(float4*)af = *(const float4*)(&As[dd][ty * 4]);                         \
      *(float4*)bf = *(const float4*)(&Es[dd][tx * 4]);                         \
      *(float4*)(bf + 4) = *(const float4*)(&Es[dd][64 + tx * 4]);              \
      _Pragma("unroll")                                                         \
      for (int i = 0; i < 4; ++i)                                               \
        _Pragma("unroll")                                                       \
        for (int j = 0; j < 8; ++j)                                             \
          ACC[i][j] = fmaf(af[i], bf[j], ACC[i][j]);                            \
    }                                                                           \
    __syncthreads();                                                            \
  }

__global__ __launch_bounds__(512) void k_argmin_f32(
    const float* __restrict__ A, const float* __restrict__ E,
    const float* __restrict__ a2, const float* __restrict__ e2,
    float* __restrict__ out_idx, int* __restrict__ idx_ws, int K) {
  __shared__ float As[16][128];
  __shared__ float Es[16][128];
  const int m0 = blockIdx.x * 128;
  const int t = threadIdx.x;
  const int tx = t & 15;
  const int ty = t >> 4;
  float a2l[4];
#pragma unroll
  for (int i = 0; i < 4; ++i) a2l[i] = a2[m0 + ty * 4 + i];
  u64 best[4];
#pragma unroll
  for (int i = 0; i < 4; ++i) best[i] = ~0ULL;
  for (int n0 = 0; n0 < K; n0 += 128) {
    float acc1[4][8], acc2[4][8];
#pragma unroll
    for (int i = 0; i < 4; ++i)
#pragma unroll
      for (int j = 0; j < 8; ++j) { acc1[i][j] = 0.f; acc2[i][j] = 0.f; }
    for (int d0 = 0; d0 < SPLIT_K; d0 += 16) KTILE(d0, acc1)
    for (int d0 = SPLIT_K; d0 < D_DIM; d0 += 16) KTILE(d0, acc2)
    float e2l[8];
#pragma unroll
    for (int j = 0; j < 8; ++j) {
      int cl = (j < 4) ? (tx * 4 + j) : (64 + tx * 4 + (j - 4));
      e2l[j] = e2[n0 + cl];
    }
#pragma unroll
    for (int i = 0; i < 4; ++i) {
#pragma unroll
      for (int j = 0; j < 8; ++j) {
        int cl = (j < 4) ? (tx * 4 + j) : (64 + tx * 4 + (j - 4));
        float S = a2l[i] + e2l[j];
        float m = acc1[i][j] + acc2[i][j];
        float s = fmaf(-2.f, m, S);
        u64 p = ((u64)mono(s) << 32) | (unsigned)(n0 + cl);
        if (p < best[i]) best[i] = p;
      }
    }
  }
#pragma unroll
  for (int m = 1; m < 16; m <<= 1) {
#pragma unroll
    for (int i = 0; i < 4; ++i) {
      u64 o = __shfl_xor(best[i], m, 64);
      if (o < best[i]) best[i] = o;
    }
  }
  if (tx == 0) {
#pragma unroll
    for (int i = 0; i < 4; ++i) {
      int row = m0 + ty * 4 + i;
      int idx = (int)(unsigned)(best[i] & 0xFFFFFFFFULL);
      out_idx[row] = (float)idx;
      idx_ws[row] = idx;
    }
  }
}

// ---------------- gather z_q, z, per-row loss partial, histogram ----------------
__global__ void k_gather(const float* __restrict__ A, const float* __restrict__ E,
                         const int* __restrict__ idx_ws,
                         float* __restrict__ out_z, float* __restrict__ rowsum,
                         int* __restrict__ counts) {
  int b = blockIdx.x;
  int t = threadIdx.x;
  int idx = idx_ws[b];
  const float4* pa = (const float4*)(A + (size_t)b * D_DIM);
  const float4* pe = (const float4*)(E + (size_t)idx * D_DIM);
  float4 a = pa[t];
  float4 e = pe[t];
  float4 z;
  z.x = a.x + (e.x - a.x);
  z.y = a.y + (e.y - a.y);
  z.z = a.z + (e.z - a.z);
  z.w = a.w + (e.w - a.w);
  ((float4*)(out_z + (size_t)b * D_DIM))[t] = z;
  float dx = a.x - e.x, dy = a.y - e.y, dz = a.z - e.z, dw = a.w - e.w;
  float ls = dx * dx + dy * dy + dz * dz + dw * dw;
#pragma unroll
  for (int off = 32; off > 0; off >>= 1) ls += __shfl_down(ls, off, 64);
  __shared__ float wsum[2];
  if ((t & 63) == 0) wsum[t >> 6] = ls;
  __syncthreads();
  if (t == 0) {
    rowsum[b] = wsum[0] + wsum[1];
    atomicAdd(&counts[idx], 1);
  }
}

// ---------------- usage stats + deterministic loss reduction ----------------
__global__ void k_stats(const int* __restrict__ counts, const float* __restrict__ rowsum,
                        float* __restrict__ out_sc, int B, int K) {
  int t = threadIdx.x;
  double ent = 0.0, tot = 0.0, S = 0.0;
  int used = 0;
  for (int k = t; k < K; k += 256) {
    int c = counts[k];
    double u = (double)c / (double)B;
    ent += u * log(u + 1e-10);
    tot += u;
    used += (c > 0) ? 1 : 0;
  }
  for (int b = t; b < B; b += 256) S += (double)rowsum[b];
  __shared__ double se[256];
  __shared__ double st[256];
  __shared__ double ss[256];
  __shared__ int su[256];
  se[t] = ent; st[t] = tot; ss[t] = S; su[t] = used;
  __syncthreads();
  for (int s = 128; s > 0; s >>= 1) {
    if (t < s) { se[t] += se[t + s]; st[t] += st[t + s]; ss[t] += ss[t + s]; su[t] += su[t + s]; }
    __syncthreads();
  }
  if (t == 0) {
    double Sm = ss[0];
    double N = (double)B * (double)D_DIM;
    out_sc[0] = (float)(0.25 * Sm / N);
    out_sc[1] = (float)(Sm / N);
    out_sc[2] = (float)exp(-se[0]);
    out_sc[3] = (float)su[0];
    out_sc[4] = (float)(st[0] / (double)K);
  }
}

extern "C" void kernel_launch(void* const* d_in, const int* in_sizes, int n_in,
                              void* d_out, int out_size, void* d_ws, size_t ws_size,
                              hipStream_t stream) {
  const float* A = (const float*)d_in[0];
  const float* E = (const float*)d_in[1];
  const int B = in_sizes[0] / D_DIM;  // 32768
  const int K = in_sizes[1] / D_DIM;  // 8192

  float* out = (float*)d_out;
  float* out_idx = out;
  float* out_z = out + B;
  float* out_sc = out + B + (size_t)B * D_DIM;

  char* ws = (char*)d_ws;
  size_t off = 0;
  float* a2 = (float*)(ws + off); off += (size_t)B * 4;
  float* e2 = (float*)(ws + off); off += (size_t)K * 4;
  int* counts = (int*)(ws + off); off += (size_t)K * 4;
  float* rowsum = (float*)(ws + off); off += (size_t)B * 4;
  int* idx_ws = (int*)(ws + off); off += (size_t)B * 4;
  int* cand_cnt = (int*)(ws + off); off += (size_t)B * 4;
  unsigned short* cand = (unsigned short*)(ws + off); off += (size_t)B * MAXC * 2;
  unsigned short* Ebf = (unsigned short*)(ws + off); off += (size_t)K * D_DIM * 2;
  const size_t need = off;

  k_init<<<(K + 255) / 256, 256, 0, stream>>>(counts, K);
  k_rowsq<<<(B + 3) / 4, 256, 0, stream>>>(A, a2, B);
  k_rowsq<<<(K + 3) / 4, 256, 0, stream>>>(E, e2, K);

  if (ws_size >= need) {
    int n8 = K * D_DIM / 8;
    k_ebf<<<(n8 + 255) / 256, 256, 0, stream>>>(E, Ebf, n8);
    k_screen<<<B / 128, 512, 0, stream>>>(A, Ebf, e2, cand_cnt, cand, K);
    k_rescore<<<B / 4, 256, 0, stream>>>(A, E, a2, e2, cand_cnt, cand, out_idx, idx_ws, K);
  } else {
    k_argmin_f32<<<B / 128, 512, 0, stream>>>(A, E, a2, e2, out_idx, idx_ws, K);
  }
  k_gather<<<B, 128, 0, stream>>>(A, E, idx_ws, out_z, rowsum, counts);
  k_stats<<<1, 256, 0, stream>>>(counts, rowsum, out_sc, B, K);
}

// Round 5
// 4850.093 us; speedup vs baseline: 7.0578x; 7.0578x over previous
//
#include <hip/hip_runtime.h>
#include <stdint.h>

#define D_DIM 512
#define SPLIT_K 384     // OpenBLAS sgemm kc (Haswell/ZEN SGEMM_DEFAULT_Q)
#define DELTA 2.0e-3f   // screening window vs FINAL row-min; worst-case need 1.52e-3
#define MAXC 32         // candidate slots per row (expect ~3.4, Poisson tail ~0)

typedef unsigned long long u64;
typedef float f32x4 __attribute__((ext_vector_type(4)));
typedef short s16x8 __attribute__((ext_vector_type(8)));

static __device__ inline unsigned short f2bf(float x) {  // RNE f32->bf16
  unsigned u = __float_as_uint(x);
  u = (u + 0x7FFFu + ((u >> 16) & 1u)) >> 16;
  return (unsigned short)u;
}
static __device__ inline unsigned mono(float f) {  // monotone float->uint
  unsigned u = __float_as_uint(f);
  return (u & 0x80000000u) ? ~u : (u | 0x80000000u);
}
static __device__ inline float unmono(unsigned m) {
  return __uint_as_float((m & 0x80000000u) ? (m & 0x7FFFFFFFu) : ~m);
}

// ---------------- init workspace (histogram only) ----------------
__global__ void k_init(int* __restrict__ counts, int K) {
  int i = blockIdx.x * blockDim.x + threadIdx.x;
  if (i < K) counts[i] = 0;
}

// ---------------- numpy-replicated row sum of squares (validated r2/r3) ----------------
__global__ void k_rowsq(const float* __restrict__ X, float* __restrict__ out, int nrows) {
  int t = threadIdx.x;
  int row = blockIdx.x * 4 + (t >> 6);
  int l = t & 63;
  if (row >= nrows) return;
  int b = l >> 4;
  int L = l & 15;
  const float* p = X + (size_t)row * D_DIM + b * 128 + L;
  float v[8];
#pragma unroll
  for (int j = 0; j < 8; ++j) {
    float x = p[16 * j];
    float sq = x * x;
    asm volatile("" : "+v"(sq));  // numpy squares then sums: no fma contraction
    v[j] = sq;
  }
  float s = ((v[0] + v[1]) + (v[2] + v[3])) + ((v[4] + v[5]) + (v[6] + v[7]));
  s += __shfl_xor(s, 8, 64);
  s += __shfl_xor(s, 4, 64);
  s += __shfl_xor(s, 2, 64);
  s += __shfl_xor(s, 1, 64);
  s += __shfl_xor(s, 16, 64);
  s += __shfl_xor(s, 32, 64);
  if (l == 0) out[row] = s;
}

// ---------------- E f32 -> bf16 ----------------
__global__ void k_ebf(const float* __restrict__ E, unsigned short* __restrict__ Ebf, int n8) {
  int i = blockIdx.x * blockDim.x + threadIdx.x;
  if (i >= n8) return;
  const float4 f0 = ((const float4*)E)[i * 2];
  const float4 f1 = ((const float4*)E)[i * 2 + 1];
  s16x8 o;
  o[0] = (short)f2bf(f0.x); o[1] = (short)f2bf(f0.y);
  o[2] = (short)f2bf(f0.z); o[3] = (short)f2bf(f0.w);
  o[4] = (short)f2bf(f1.x); o[5] = (short)f2bf(f1.y);
  o[6] = (short)f2bf(f1.z); o[7] = (short)f2bf(f1.w);
  ((s16x8*)Ebf)[i] = o;
}

// ---------------- two-phase MFMA bf16 screening ----------------
// Phase 1: full GEMM pass -> exact per-row min of s~ (LDS, monotone u32).
// Phase 2: identical-bitwise GEMM pass -> collect k with s~ <= rowmin + DELTA.
__global__ __launch_bounds__(512) void k_screen(
    const float* __restrict__ A, const unsigned short* __restrict__ Ebf,
    const float* __restrict__ e2, int* __restrict__ cand_cnt,
    unsigned short* __restrict__ cand, int K) {
  __shared__ unsigned runmin[128];
  __shared__ unsigned cnt[128];
  __shared__ unsigned short list[128 * MAXC];
  __shared__ __align__(16) char Alds[128 * 1024];  // 128 rows x 512 bf16, swizzled

  const int t = threadIdx.x;
  const int m0 = blockIdx.x * 128;

  if (t < 128) { runmin[t] = 0xFFFFFFFFu; cnt[t] = 0; }

  // stage A -> bf16 LDS, 16B chunks, byte XOR-swizzle ((row&7)<<4)
  {
    int row = t >> 2;
    int s4 = t & 3;
    const float* ar = A + (size_t)(m0 + row) * D_DIM;
#pragma unroll
    for (int c = 0; c < 16; ++c) {
      int ch = s4 * 16 + c;  // 16B chunk = 8 bf16
      float4 f0 = *(const float4*)(ar + ch * 8);
      float4 f1 = *(const float4*)(ar + ch * 8 + 4);
      s16x8 o;
      o[0] = (short)f2bf(f0.x); o[1] = (short)f2bf(f0.y);
      o[2] = (short)f2bf(f0.z); o[3] = (short)f2bf(f0.w);
      o[4] = (short)f2bf(f1.x); o[5] = (short)f2bf(f1.y);
      o[6] = (short)f2bf(f1.z); o[7] = (short)f2bf(f1.w);
      int off = ((row * 64 + ch) * 16) ^ ((row & 7) << 4);
      *(s16x8*)(Alds + off) = o;
    }
  }
  __syncthreads();

  const int lane = t & 63;
  const int wid = t >> 6;
  const int wm = wid >> 2;   // 0..1: rows wm*64..+63
  const int wn = wid & 3;    // 0..3: cols wn*32..+31
  const int l15 = lane & 15;
  const int lhi = lane >> 4; // 0..3

  // -------- phase 1: row minima --------
  for (int n0 = 0; n0 < K; n0 += 128) {
    f32x4 acc[4][2];
#pragma unroll
    for (int r = 0; r < 4; ++r)
#pragma unroll
      for (int c = 0; c < 2; ++c) acc[r][c] = (f32x4){0.f, 0.f, 0.f, 0.f};
    const unsigned short* B0 = Ebf + (size_t)(n0 + wn * 32 + l15) * D_DIM + lhi * 8;
    const unsigned short* B1 = B0 + 16 * D_DIM;
#pragma unroll
    for (int dk = 0; dk < 16; ++dk) {
      s16x8 b0 = *(const s16x8*)(B0 + dk * 32);
      s16x8 b1 = *(const s16x8*)(B1 + dk * 32);
      s16x8 af[4];
#pragma unroll
      for (int r = 0; r < 4; ++r) {
        int row = wm * 64 + r * 16 + l15;
        int off = ((row * 64 + dk * 4 + lhi) * 16) ^ ((row & 7) << 4);
        af[r] = *(const s16x8*)(Alds + off);
      }
#pragma unroll
      for (int r = 0; r < 4; ++r) {
        acc[r][0] = __builtin_amdgcn_mfma_f32_16x16x32_bf16(af[r], b0, acc[r][0], 0, 0, 0);
        acc[r][1] = __builtin_amdgcn_mfma_f32_16x16x32_bf16(af[r], b1, acc[r][1], 0, 0, 0);
      }
    }
    float e2c0 = e2[n0 + wn * 32 + l15];
    float e2c1 = e2[n0 + wn * 32 + 16 + l15];
#pragma unroll
    for (int r = 0; r < 4; ++r)
#pragma unroll
      for (int g = 0; g < 4; ++g) {
        float s0 = fmaf(-2.f, acc[r][0][g], e2c0);
        float s1 = fmaf(-2.f, acc[r][1][g], e2c1);
        float mn = fminf(s0, s1);
        mn = fminf(mn, __shfl_xor(mn, 1, 64));
        mn = fminf(mn, __shfl_xor(mn, 2, 64));
        mn = fminf(mn, __shfl_xor(mn, 4, 64));
        mn = fminf(mn, __shfl_xor(mn, 8, 64));
        if (l15 == 0) atomicMin(&runmin[wm * 64 + r * 16 + lhi * 4 + g], mono(mn));
      }
  }
  __syncthreads();

  // -------- phase 2: collect vs final min --------
  float thr[4][4];
#pragma unroll
  for (int r = 0; r < 4; ++r)
#pragma unroll
    for (int g = 0; g < 4; ++g)
      thr[r][g] = unmono(runmin[wm * 64 + r * 16 + lhi * 4 + g]) + DELTA;

  for (int n0 = 0; n0 < K; n0 += 128) {
    f32x4 acc[4][2];
#pragma unroll
    for (int r = 0; r < 4; ++r)
#pragma unroll
      for (int c = 0; c < 2; ++c) acc[r][c] = (f32x4){0.f, 0.f, 0.f, 0.f};
    const unsigned short* B0 = Ebf + (size_t)(n0 + wn * 32 + l15) * D_DIM + lhi * 8;
    const unsigned short* B1 = B0 + 16 * D_DIM;
#pragma unroll
    for (int dk = 0; dk < 16; ++dk) {
      s16x8 b0 = *(const s16x8*)(B0 + dk * 32);
      s16x8 b1 = *(const s16x8*)(B1 + dk * 32);
      s16x8 af[4];
#pragma unroll
      for (int r = 0; r < 4; ++r) {
        int row = wm * 64 + r * 16 + l15;
        int off = ((row * 64 + dk * 4 + lhi) * 16) ^ ((row & 7) << 4);
        af[r] = *(const s16x8*)(Alds + off);
      }
#pragma unroll
      for (int r = 0; r < 4; ++r) {
        acc[r][0] = __builtin_amdgcn_mfma_f32_16x16x32_bf16(af[r], b0, acc[r][0], 0, 0, 0);
        acc[r][1] = __builtin_amdgcn_mfma_f32_16x16x32_bf16(af[r], b1, acc[r][1], 0, 0, 0);
      }
    }
    float e2c0 = e2[n0 + wn * 32 + l15];
    float e2c1 = e2[n0 + wn * 32 + 16 + l15];
#pragma unroll
    for (int r = 0; r < 4; ++r)
#pragma unroll
      for (int g = 0; g < 4; ++g) {
        float s0 = fmaf(-2.f, acc[r][0][g], e2c0);
        float s1 = fmaf(-2.f, acc[r][1][g], e2c1);
        int row = wm * 64 + r * 16 + lhi * 4 + g;
        if (s0 <= thr[r][g]) {
          unsigned p = atomicAdd(&cnt[row], 1u);
          if (p < MAXC) list[row * MAXC + p] = (unsigned short)(n0 + wn * 32 + l15);
        }
        if (s1 <= thr[r][g]) {
          unsigned p = atomicAdd(&cnt[row], 1u);
          if (p < MAXC) list[row * MAXC + p] = (unsigned short)(n0 + wn * 32 + 16 + l15);
        }
      }
  }
  __syncthreads();
  {
    int row = t >> 2;
    unsigned c = cnt[row];
    if ((t & 3) == 0) cand_cnt[m0 + row] = (int)c;
    unsigned cc = c < MAXC ? c : MAXC;
    for (unsigned p = t & 3; p < cc; p += 4)
      cand[(size_t)(m0 + row) * MAXC + p] = list[row * MAXC + p];
  }
}

// ---------------- exact numpy-f32 score ----------------
static __device__ inline u64 exact_pack(const float* __restrict__ ar,
                                        const float* __restrict__ er,
                                        float a2r, float e2k, int k) {
  float acc1 = 0.f, acc2 = 0.f;
  for (int d = 0; d < SPLIT_K; d += 4) {
    float4 a = *(const float4*)(ar + d);
    float4 e = *(const float4*)(er + d);
    acc1 = fmaf(a.x, e.x, acc1); acc1 = fmaf(a.y, e.y, acc1);
    acc1 = fmaf(a.z, e.z, acc1); acc1 = fmaf(a.w, e.w, acc1);
  }
  for (int d = SPLIT_K; d < D_DIM; d += 4) {
    float4 a = *(const float4*)(ar + d);
    float4 e = *(const float4*)(er + d);
    acc2 = fmaf(a.x, e.x, acc2); acc2 = fmaf(a.y, e.y, acc2);
    acc2 = fmaf(a.z, e.z, acc2); acc2 = fmaf(a.w, e.w, acc2);
  }
  float M = acc1 + acc2;          // BLAS kc-split merge
  float S = a2r + e2k;            // fl(a2 + e2)
  float s = fmaf(-2.f, M, S);     // fl(S - 2M)
  return ((u64)mono(s) << 32) | (unsigned)k;
}

// ---------------- exact rescore + fused gather/z/loss/histogram ----------------
__global__ __launch_bounds__(256) void k_rescore(
    const float* __restrict__ A, const float* __restrict__ E,
    const float* __restrict__ a2, const float* __restrict__ e2,
    const int* __restrict__ cand_cnt, const unsigned short* __restrict__ cand,
    float* __restrict__ out_idx, float* __restrict__ out_z,
    float* __restrict__ rowsum, int* __restrict__ counts, int K) {
  int lane = threadIdx.x & 63;
  int r = blockIdx.x * 4 + (threadIdx.x >> 6);
  int c = cand_cnt[r];
  const float* ar = A + (size_t)r * D_DIM;
  float a2r = a2[r];
  u64 best = ~0ULL;
  if (c <= MAXC) {
    if (lane < c) {
      int k = cand[(size_t)r * MAXC + lane];
      best = exact_pack(ar, E + (size_t)k * D_DIM, a2r, e2[k], k);
    }
  } else {  // overflow net: exact scan of all K (deterministic; ~never hit)
    for (int k = lane; k < K; k += 64) {
      u64 p = exact_pack(ar, E + (size_t)k * D_DIM, a2r, e2[k], k);
      if (p < best) best = p;
    }
  }
#pragma unroll
  for (int m = 1; m < 64; m <<= 1) {
    u64 o = __shfl_xor(best, m, 64);
    if (o < best) best = o;
  }
  int idx = (int)(unsigned)(best & 0xFFFFFFFFULL);

  // fused gather: z, per-row loss partial (each lane: 8 cols)
  const float4* pa = (const float4*)(ar) + lane * 2;
  const float4* pe = (const float4*)(E + (size_t)idx * D_DIM) + lane * 2;
  float4* pz = (float4*)(out_z + (size_t)r * D_DIM) + lane * 2;
  float ls = 0.f;
#pragma unroll
  for (int q = 0; q < 2; ++q) {
    float4 a = pa[q];
    float4 e = pe[q];
    float4 z;
    z.x = a.x + (e.x - a.x);  // replicate ref f32 ops exactly
    z.y = a.y + (e.y - a.y);
    z.z = a.z + (e.z - a.z);
    z.w = a.w + (e.w - a.w);
    pz[q] = z;
    float dx = a.x - e.x, dy = a.y - e.y, dz = a.z - e.z, dw = a.w - e.w;
    ls += dx * dx + dy * dy + dz * dz + dw * dw;
  }
#pragma unroll
  for (int m = 1; m < 64; m <<= 1) ls += __shfl_xor(ls, m, 64);
  if (lane == 0) {
    out_idx[r] = (float)idx;
    rowsum[r] = ls;
    atomicAdd(&counts[idx], 1);
  }
}

// ---------------- validated round-3 f32 argmin (ws-size fallback) ----------------
#define KTILE(D0, ACC)                                                          \
  {                                                                             \
    int r = t >> 2;                                                             \
    int c4 = (t & 3) << 2;                                                      \
    float4 va = *(const float4*)(A + (size_t)(m0 + r) * D_DIM + (D0) + c4);     \
    As[c4 + 0][r] = va.x; As[c4 + 1][r] = va.y;                                 \
    As[c4 + 2][r] = va.z; As[c4 + 3][r] = va.w;                                 \
    float4 vb = *(const float4*)(E + (size_t)(n0 + r) * D_DIM + (D0) + c4);     \
    Es[c4 + 0][r] = vb.x; Es[c4 + 1][r] = vb.y;                                 \
    Es[c4 + 2][r] = vb.z; Es[c4 + 3][r] = vb.w;                                 \
    __syncthreads();                                                            \
    _Pragma("unroll")                                                           \
    for (int dd = 0; dd < 16; ++dd) {                                           \
      float af[4], bf[8];                                                       \
      *(float4*)af = *(const float4*)(&As[dd][ty * 4]);                         \
      *(float4*)bf = *(const float4*)(&Es[dd][tx * 4]);                         \
      *(float4*)(bf + 4) = *(const float4*)(&Es[dd][64 + tx * 4]);              \
      _Pragma("unroll")                                                         \
      for (int i = 0; i < 4; ++i)                                               \
        _Pragma("unroll")                                                       \
        for (int j = 0; j < 8; ++j)                                             \
          ACC[i][j] = fmaf(af[i], bf[j], ACC[i][j]);                            \
    }                                                                           \
    __syncthreads();                                                            \
  }

__global__ __launch_bounds__(512) void k_argmin_f32(
    const float* __restrict__ A, const float* __restrict__ E,
    const float* __restrict__ a2, const float* __restrict__ e2,
    float* __restrict__ out_idx, int* __restrict__ idx_ws, int K) {
  __shared__ float As[16][128];
  __shared__ float Es[16][128];
  const int m0 = blockIdx.x * 128;
  const int t = threadIdx.x;
  const int tx = t & 15;
  const int ty = t >> 4;
  float a2l[4];
#pragma unroll
  for (int i = 0; i < 4; ++i) a2l[i] = a2[m0 + ty * 4 + i];
  u64 best[4];
#pragma unroll
  for (int i = 0; i < 4; ++i) best[i] = ~0ULL;
  for (int n0 = 0; n0 < K; n0 += 128) {
    float acc1[4][8], acc2[4][8];
#pragma unroll
    for (int i = 0; i < 4; ++i)
#pragma unroll
      for (int j = 0; j < 8; ++j) { acc1[i][j] = 0.f; acc2[i][j] = 0.f; }
    for (int d0 = 0; d0 < SPLIT_K; d0 += 16) KTILE(d0, acc1)
    for (int d0 = SPLIT_K; d0 < D_DIM; d0 += 16) KTILE(d0, acc2)
    float e2l[8];
#pragma unroll
    for (int j = 0; j < 8; ++j) {
      int cl = (j < 4) ? (tx * 4 + j) : (64 + tx * 4 + (j - 4));
      e2l[j] = e2[n0 + cl];
    }
#pragma unroll
    for (int i = 0; i < 4; ++i) {
#pragma unroll
      for (int j = 0; j < 8; ++j) {
        int cl = (j < 4) ? (tx * 4 + j) : (64 + tx * 4 + (j - 4));
        float S = a2l[i] + e2l[j];
        float m = acc1[i][j] + acc2[i][j];
        float s = fmaf(-2.f, m, S);
        u64 p = ((u64)mono(s) << 32) | (unsigned)(n0 + cl);
        if (p < best[i]) best[i] = p;
      }
    }
  }
#pragma unroll
  for (int m = 1; m < 16; m <<= 1) {
#pragma unroll
    for (int i = 0; i < 4; ++i) {
      u64 o = __shfl_xor(best[i], m, 64);
      if (o < best[i]) best[i] = o;
    }
  }
  if (tx == 0) {
#pragma unroll
    for (int i = 0; i < 4; ++i) {
      int row = m0 + ty * 4 + i;
      int idx = (int)(unsigned)(best[i] & 0xFFFFFFFFULL);
      out_idx[row] = (float)idx;
      idx_ws[row] = idx;
    }
  }
}

__global__ void k_gather(const float* __restrict__ A, const float* __restrict__ E,
                         const int* __restrict__ idx_ws,
                         float* __restrict__ out_z, float* __restrict__ rowsum,
                         int* __restrict__ counts) {
  int b = blockIdx.x;
  int t = threadIdx.x;
  int idx = idx_ws[b];
  const float4* pa = (const float4*)(A + (size_t)b * D_DIM);
  const float4* pe = (const float4*)(E + (size_t)idx * D_DIM);
  float4 a = pa[t];
  float4 e = pe[t];
  float4 z;
  z.x = a.x + (e.x - a.x);
  z.y = a.y + (e.y - a.y);
  z.z = a.z + (e.z - a.z);
  z.w = a.w + (e.w - a.w);
  ((float4*)(out_z + (size_t)b * D_DIM))[t] = z;
  float dx = a.x - e.x, dy = a.y - e.y, dz = a.z - e.z, dw = a.w - e.w;
  float ls = dx * dx + dy * dy + dz * dz + dw * dw;
#pragma unroll
  for (int off = 32; off > 0; off >>= 1) ls += __shfl_down(ls, off, 64);
  __shared__ float wsum[2];
  if ((t & 63) == 0) wsum[t >> 6] = ls;
  __syncthreads();
  if (t == 0) {
    rowsum[b] = wsum[0] + wsum[1];
    atomicAdd(&counts[idx], 1);
  }
}

// ---------------- usage stats + deterministic loss reduction ----------------
__global__ void k_stats(const int* __restrict__ counts, const float* __restrict__ rowsum,
                        float* __restrict__ out_sc, int B, int K) {
  int t = threadIdx.x;
  double ent = 0.0, tot = 0.0, S = 0.0;
  int used = 0;
  for (int k = t; k < K; k += 256) {
    int c = counts[k];
    double u = (double)c / (double)B;
    ent += u * log(u + 1e-10);
    tot += u;
    used += (c > 0) ? 1 : 0;
  }
  for (int b = t; b < B; b += 256) S += (double)rowsum[b];
  __shared__ double se[256];
  __shared__ double st[256];
  __shared__ double ss[256];
  __shared__ int su[256];
  se[t] = ent; st[t] = tot; ss[t] = S; su[t] = used;
  __syncthreads();
  for (int s = 128; s > 0; s >>= 1) {
    if (t < s) { se[t] += se[t + s]; st[t] += st[t + s]; ss[t] += ss[t + s]; su[t] += su[t + s]; }
    __syncthreads();
  }
  if (t == 0) {
    double Sm = ss[0];
    double N = (double)B * (double)D_DIM;
    out_sc[0] = (float)(0.25 * Sm / N);
    out_sc[1] = (float)(Sm / N);
    out_sc[2] = (float)exp(-se[0]);
    out_sc[3] = (float)su[0];
    out_sc[4] = (float)(st[0] / (double)K);
  }
}

extern "C" void kernel_launch(void* const* d_in, const int* in_sizes, int n_in,
                              void* d_out, int out_size, void* d_ws, size_t ws_size,
                              hipStream_t stream) {
  const float* A = (const float*)d_in[0];
  const float* E = (const float*)d_in[1];
  const int B = in_sizes[0] / D_DIM;  // 32768
  const int K = in_sizes[1] / D_DIM;  // 8192

  float* out = (float*)d_out;
  float* out_idx = out;
  float* out_z = out + B;
  float* out_sc = out + B + (size_t)B * D_DIM;

  char* ws = (char*)d_ws;
  size_t off = 0;
  float* a2 = (float*)(ws + off); off += (size_t)B * 4;
  float* e2 = (float*)(ws + off); off += (size_t)K * 4;
  int* counts = (int*)(ws + off); off += (size_t)K * 4;
  float* rowsum = (float*)(ws + off); off += (size_t)B * 4;
  int* idx_ws = (int*)(ws + off); off += (size_t)B * 4;
  int* cand_cnt = (int*)(ws + off); off += (size_t)B * 4;
  unsigned short* cand = (unsigned short*)(ws + off); off += (size_t)B * MAXC * 2;
  unsigned short* Ebf = (unsigned short*)(ws + off); off += (size_t)K * D_DIM * 2;
  const size_t need = off;

  k_init<<<(K + 255) / 256, 256, 0, stream>>>(counts, K);
  k_rowsq<<<(B + 3) / 4, 256, 0, stream>>>(A, a2, B);
  k_rowsq<<<(K + 3) / 4, 256, 0, stream>>>(E, e2, K);

  if (ws_size >= need) {
    int n8 = K * D_DIM / 8;
    k_ebf<<<(n8 + 255) / 256, 256, 0, stream>>>(E, Ebf, n8);
    k_screen<<<B / 128, 512, 0, stream>>>(A, Ebf, e2, cand_cnt, cand, K);
    k_rescore<<<B / 4, 256, 0, stream>>>(A, E, a2, e2, cand_cnt, cand,
                                         out_idx, out_z, rowsum, counts, K);
  } else {
    k_argmin_f32<<<B / 128, 512, 0, stream>>>(A, E, a2, e2, out_idx, idx_ws, K);
    k_gather<<<B, 128, 0, stream>>>(A, E, idx_ws, out_z, rowsum, counts);
  }
  k_stats<<<1, 256, 0, stream>>>(counts, rowsum, out_sc, B, K);
}

// Round 6
// 4212.184 us; speedup vs baseline: 8.1267x; 1.1514x over previous
//
#include <hip/hip_runtime.h>
#include <stdint.h>

#define D_DIM 512
#define ESTRIDE 528     // skewed E row stride (floats): 2112B = 33 lines, breaks L1/L2 set conflicts
#define SPLIT_K 384     // OpenBLAS sgemm kc (Haswell/ZEN SGEMM_DEFAULT_Q)
#define DELTA 2.0e-3f   // screening window vs FINAL row-min; worst-case need 1.52e-3
#define MAXC 32         // candidate slots per row (expect ~8, Poisson tail ~0)

typedef unsigned long long u64;
typedef float f32x4 __attribute__((ext_vector_type(4)));
typedef short s16x8 __attribute__((ext_vector_type(8)));

static __device__ inline unsigned short f2bf(float x) {  // RNE f32->bf16
  unsigned u = __float_as_uint(x);
  u = (u + 0x7FFFu + ((u >> 16) & 1u)) >> 16;
  return (unsigned short)u;
}
static __device__ inline unsigned mono(float f) {  // monotone float->uint
  unsigned u = __float_as_uint(f);
  return (u & 0x80000000u) ? ~u : (u | 0x80000000u);
}
static __device__ inline float unmono(unsigned m) {
  return __uint_as_float((m & 0x80000000u) ? (m & 0x7FFFFFFFu) : ~m);
}

// ---------------- init workspace (histogram only) ----------------
__global__ void k_init(int* __restrict__ counts, int K) {
  int i = blockIdx.x * blockDim.x + threadIdx.x;
  if (i < K) counts[i] = 0;
}

// ---------------- numpy-replicated row sum of squares (validated r2/r3) ----------------
__global__ void k_rowsq(const float* __restrict__ X, float* __restrict__ out, int nrows) {
  int t = threadIdx.x;
  int row = blockIdx.x * 4 + (t >> 6);
  int l = t & 63;
  if (row >= nrows) return;
  int b = l >> 4;
  int L = l & 15;
  const float* p = X + (size_t)row * D_DIM + b * 128 + L;
  float v[8];
#pragma unroll
  for (int j = 0; j < 8; ++j) {
    float x = p[16 * j];
    float sq = x * x;
    asm volatile("" : "+v"(sq));  // numpy squares then sums: no fma contraction
    v[j] = sq;
  }
  float s = ((v[0] + v[1]) + (v[2] + v[3])) + ((v[4] + v[5]) + (v[6] + v[7]));
  s += __shfl_xor(s, 8, 64);
  s += __shfl_xor(s, 4, 64);
  s += __shfl_xor(s, 2, 64);
  s += __shfl_xor(s, 1, 64);
  s += __shfl_xor(s, 16, 64);
  s += __shfl_xor(s, 32, 64);
  if (l == 0) out[row] = s;
}

// ---------------- E f32 -> bf16 ----------------
__global__ void k_ebf(const float* __restrict__ E, unsigned short* __restrict__ Ebf, int n8) {
  int i = blockIdx.x * blockDim.x + threadIdx.x;
  if (i >= n8) return;
  const float4 f0 = ((const float4*)E)[i * 2];
  const float4 f1 = ((const float4*)E)[i * 2 + 1];
  s16x8 o;
  o[0] = (short)f2bf(f0.x); o[1] = (short)f2bf(f0.y);
  o[2] = (short)f2bf(f0.z); o[3] = (short)f2bf(f0.w);
  o[4] = (short)f2bf(f1.x); o[5] = (short)f2bf(f1.y);
  o[6] = (short)f2bf(f1.z); o[7] = (short)f2bf(f1.w);
  ((s16x8*)Ebf)[i] = o;
}

// ---------------- E f32 -> skewed copy (row stride 528 floats) ----------------
__global__ void k_eskew(const float* __restrict__ E, float* __restrict__ Es, int n4) {
  int i = blockIdx.x * blockDim.x + threadIdx.x;  // one float4 per thread
  if (i >= n4) return;
  int row = i >> 7;          // 128 float4 per row
  int c = i & 127;
  float4 v = ((const float4*)(E + (size_t)row * D_DIM))[c];
  ((float4*)(Es + (size_t)row * ESTRIDE))[c] = v;
}

// ---------------- two-phase MFMA bf16 screening (validated r5) ----------------
__global__ __launch_bounds__(512) void k_screen(
    const float* __restrict__ A, const unsigned short* __restrict__ Ebf,
    const float* __restrict__ e2, int* __restrict__ cand_cnt,
    unsigned short* __restrict__ cand, int K) {
  __shared__ unsigned runmin[128];
  __shared__ unsigned cnt[128];
  __shared__ unsigned short list[128 * MAXC];
  __shared__ __align__(16) char Alds[128 * 1024];  // 128 rows x 512 bf16, swizzled

  const int t = threadIdx.x;
  const int m0 = blockIdx.x * 128;

  if (t < 128) { runmin[t] = 0xFFFFFFFFu; cnt[t] = 0; }

  // stage A -> bf16 LDS, 16B chunks, byte XOR-swizzle ((row&7)<<4)
  {
    int row = t >> 2;
    int s4 = t & 3;
    const float* ar = A + (size_t)(m0 + row) * D_DIM;
#pragma unroll
    for (int c = 0; c < 16; ++c) {
      int ch = s4 * 16 + c;  // 16B chunk = 8 bf16
      float4 f0 = *(const float4*)(ar + ch * 8);
      float4 f1 = *(const float4*)(ar + ch * 8 + 4);
      s16x8 o;
      o[0] = (short)f2bf(f0.x); o[1] = (short)f2bf(f0.y);
      o[2] = (short)f2bf(f0.z); o[3] = (short)f2bf(f0.w);
      o[4] = (short)f2bf(f1.x); o[5] = (short)f2bf(f1.y);
      o[6] = (short)f2bf(f1.z); o[7] = (short)f2bf(f1.w);
      int off = ((row * 64 + ch) * 16) ^ ((row & 7) << 4);
      *(s16x8*)(Alds + off) = o;
    }
  }
  __syncthreads();

  const int lane = t & 63;
  const int wid = t >> 6;
  const int wm = wid >> 2;   // 0..1: rows wm*64..+63
  const int wn = wid & 3;    // 0..3: cols wn*32..+31
  const int l15 = lane & 15;
  const int lhi = lane >> 4; // 0..3

  // -------- phase 1: row minima --------
  for (int n0 = 0; n0 < K; n0 += 128) {
    f32x4 acc[4][2];
#pragma unroll
    for (int r = 0; r < 4; ++r)
#pragma unroll
      for (int c = 0; c < 2; ++c) acc[r][c] = (f32x4){0.f, 0.f, 0.f, 0.f};
    const unsigned short* B0 = Ebf + (size_t)(n0 + wn * 32 + l15) * D_DIM + lhi * 8;
    const unsigned short* B1 = B0 + 16 * D_DIM;
#pragma unroll
    for (int dk = 0; dk < 16; ++dk) {
      s16x8 b0 = *(const s16x8*)(B0 + dk * 32);
      s16x8 b1 = *(const s16x8*)(B1 + dk * 32);
      s16x8 af[4];
#pragma unroll
      for (int r = 0; r < 4; ++r) {
        int row = wm * 64 + r * 16 + l15;
        int off = ((row * 64 + dk * 4 + lhi) * 16) ^ ((row & 7) << 4);
        af[r] = *(const s16x8*)(Alds + off);
      }
#pragma unroll
      for (int r = 0; r < 4; ++r) {
        acc[r][0] = __builtin_amdgcn_mfma_f32_16x16x32_bf16(af[r], b0, acc[r][0], 0, 0, 0);
        acc[r][1] = __builtin_amdgcn_mfma_f32_16x16x32_bf16(af[r], b1, acc[r][1], 0, 0, 0);
      }
    }
    float e2c0 = e2[n0 + wn * 32 + l15];
    float e2c1 = e2[n0 + wn * 32 + 16 + l15];
#pragma unroll
    for (int r = 0; r < 4; ++r)
#pragma unroll
      for (int g = 0; g < 4; ++g) {
        float s0 = fmaf(-2.f, acc[r][0][g], e2c0);
        float s1 = fmaf(-2.f, acc[r][1][g], e2c1);
        float mn = fminf(s0, s1);
        mn = fminf(mn, __shfl_xor(mn, 1, 64));
        mn = fminf(mn, __shfl_xor(mn, 2, 64));
        mn = fminf(mn, __shfl_xor(mn, 4, 64));
        mn = fminf(mn, __shfl_xor(mn, 8, 64));
        if (l15 == 0) atomicMin(&runmin[wm * 64 + r * 16 + lhi * 4 + g], mono(mn));
      }
  }
  __syncthreads();

  // -------- phase 2: collect vs final min --------
  float thr[4][4];
#pragma unroll
  for (int r = 0; r < 4; ++r)
#pragma unroll
    for (int g = 0; g < 4; ++g)
      thr[r][g] = unmono(runmin[wm * 64 + r * 16 + lhi * 4 + g]) + DELTA;

  for (int n0 = 0; n0 < K; n0 += 128) {
    f32x4 acc[4][2];
#pragma unroll
    for (int r = 0; r < 4; ++r)
#pragma unroll
      for (int c = 0; c < 2; ++c) acc[r][c] = (f32x4){0.f, 0.f, 0.f, 0.f};
    const unsigned short* B0 = Ebf + (size_t)(n0 + wn * 32 + l15) * D_DIM + lhi * 8;
    const unsigned short* B1 = B0 + 16 * D_DIM;
#pragma unroll
    for (int dk = 0; dk < 16; ++dk) {
      s16x8 b0 = *(const s16x8*)(B0 + dk * 32);
      s16x8 b1 = *(const s16x8*)(B1 + dk * 32);
      s16x8 af[4];
#pragma unroll
      for (int r = 0; r < 4; ++r) {
        int row = wm * 64 + r * 16 + l15;
        int off = ((row * 64 + dk * 4 + lhi) * 16) ^ ((row & 7) << 4);
        af[r] = *(const s16x8*)(Alds + off);
      }
#pragma unroll
      for (int r = 0; r < 4; ++r) {
        acc[r][0] = __builtin_amdgcn_mfma_f32_16x16x32_bf16(af[r], b0, acc[r][0], 0, 0, 0);
        acc[r][1] = __builtin_amdgcn_mfma_f32_16x16x32_bf16(af[r], b1, acc[r][1], 0, 0, 0);
      }
    }
    float e2c0 = e2[n0 + wn * 32 + l15];
    float e2c1 = e2[n0 + wn * 32 + 16 + l15];
#pragma unroll
    for (int r = 0; r < 4; ++r)
#pragma unroll
      for (int g = 0; g < 4; ++g) {
        float s0 = fmaf(-2.f, acc[r][0][g], e2c0);
        float s1 = fmaf(-2.f, acc[r][1][g], e2c1);
        int row = wm * 64 + r * 16 + lhi * 4 + g;
        if (s0 <= thr[r][g]) {
          unsigned p = atomicAdd(&cnt[row], 1u);
          if (p < MAXC) list[row * MAXC + p] = (unsigned short)(n0 + wn * 32 + l15);
        }
        if (s1 <= thr[r][g]) {
          unsigned p = atomicAdd(&cnt[row], 1u);
          if (p < MAXC) list[row * MAXC + p] = (unsigned short)(n0 + wn * 32 + 16 + l15);
        }
      }
  }
  __syncthreads();
  {
    int row = t >> 2;
    unsigned c = cnt[row];
    if ((t & 3) == 0) cand_cnt[m0 + row] = (int)c;
    unsigned cc = c < MAXC ? c : MAXC;
    for (unsigned p = t & 3; p < cc; p += 4)
      cand[(size_t)(m0 + row) * MAXC + p] = list[row * MAXC + p];
  }
}

// ---------------- exact numpy-f32 score (reads skewed E) ----------------
static __device__ inline u64 exact_pack(const float* __restrict__ ar,
                                        const float* __restrict__ er,
                                        float a2r, float e2k, int k) {
  float acc1 = 0.f, acc2 = 0.f;
  for (int d = 0; d < SPLIT_K; d += 4) {
    float4 a = *(const float4*)(ar + d);
    float4 e = *(const float4*)(er + d);
    acc1 = fmaf(a.x, e.x, acc1); acc1 = fmaf(a.y, e.y, acc1);
    acc1 = fmaf(a.z, e.z, acc1); acc1 = fmaf(a.w, e.w, acc1);
  }
  for (int d = SPLIT_K; d < D_DIM; d += 4) {
    float4 a = *(const float4*)(ar + d);
    float4 e = *(const float4*)(er + d);
    acc2 = fmaf(a.x, e.x, acc2); acc2 = fmaf(a.y, e.y, acc2);
    acc2 = fmaf(a.z, e.z, acc2); acc2 = fmaf(a.w, e.w, acc2);
  }
  float M = acc1 + acc2;          // BLAS kc-split merge
  float S = a2r + e2k;            // fl(a2 + e2)
  float s = fmaf(-2.f, M, S);     // fl(S - 2M)
  return ((u64)mono(s) << 32) | (unsigned)k;
}

// ---------------- exact rescore + fused gather/z/loss/histogram ----------------
__global__ __launch_bounds__(256) void k_rescore(
    const float* __restrict__ A, const float* __restrict__ Eskew,
    const float* __restrict__ a2, const float* __restrict__ e2,
    const int* __restrict__ cand_cnt, const unsigned short* __restrict__ cand,
    float* __restrict__ out_idx, float* __restrict__ out_z,
    float* __restrict__ rowsum, int* __restrict__ counts, int K) {
  int lane = threadIdx.x & 63;
  int r = blockIdx.x * 4 + (threadIdx.x >> 6);
  int c = cand_cnt[r];
  const float* ar = A + (size_t)r * D_DIM;
  float a2r = a2[r];
  u64 best = ~0ULL;
  if (c <= MAXC) {
    if (lane < c) {
      int k = cand[(size_t)r * MAXC + lane];
      best = exact_pack(ar, Eskew + (size_t)k * ESTRIDE, a2r, e2[k], k);
    }
  } else {  // overflow net: exact scan of all K (deterministic; ~never hit)
    for (int k = lane; k < K; k += 64) {
      u64 p = exact_pack(ar, Eskew + (size_t)k * ESTRIDE, a2r, e2[k], k);
      if (p < best) best = p;
    }
  }
#pragma unroll
  for (int m = 1; m < 64; m <<= 1) {
    u64 o = __shfl_xor(best, m, 64);
    if (o < best) best = o;
  }
  int idx = (int)(unsigned)(best & 0xFFFFFFFFULL);

  // fused gather: z, per-row loss partial (each lane: 8 cols)
  const float4* pa = (const float4*)(ar) + lane * 2;
  const float4* pe = (const float4*)(Eskew + (size_t)idx * ESTRIDE) + lane * 2;
  float4* pz = (float4*)(out_z + (size_t)r * D_DIM) + lane * 2;
  float ls = 0.f;
#pragma unroll
  for (int q = 0; q < 2; ++q) {
    float4 a = pa[q];
    float4 e = pe[q];
    float4 z;
    z.x = a.x + (e.x - a.x);  // replicate ref f32 ops exactly
    z.y = a.y + (e.y - a.y);
    z.z = a.z + (e.z - a.z);
    z.w = a.w + (e.w - a.w);
    pz[q] = z;
    float dx = a.x - e.x, dy = a.y - e.y, dz = a.z - e.z, dw = a.w - e.w;
    ls += dx * dx + dy * dy + dz * dz + dw * dw;
  }
#pragma unroll
  for (int m = 1; m < 64; m <<= 1) ls += __shfl_xor(ls, m, 64);
  if (lane == 0) {
    out_idx[r] = (float)idx;
    rowsum[r] = ls;
    atomicAdd(&counts[idx], 1);
  }
}

// ---------------- validated round-3 f32 argmin (ws-size fallback) ----------------
#define KTILE(D0, ACC)                                                          \
  {                                                                             \
    int r = t >> 2;                                                             \
    int c4 = (t & 3) << 2;                                                      \
    float4 va = *(const float4*)(A + (size_t)(m0 + r) * D_DIM + (D0) + c4);     \
    As[c4 + 0][r] = va.x; As[c4 + 1][r] = va.y;                                 \
    As[c4 + 2][r] = va.z; As[c4 + 3][r] = va.w;                                 \
    float4 vb = *(const float4*)(E + (size_t)(n0 + r) * D_DIM + (D0) + c4);     \
    Es[c4 + 0][r] = vb.x; Es[c4 + 1][r] = vb.y;                                 \
    Es[c4 + 2][r] = vb.z; Es[c4 + 3][r] = vb.w;                                 \
    __syncthreads();                                                            \
    _Pragma("unroll")                                                           \
    for (int dd = 0; dd < 16; ++dd) {                                           \
      float af[4], bf[8];                                                       \
      *(float4*)af = *(const float4*)(&As[dd][ty * 4]);                         \
      *(float4*)bf = *(const float4*)(&Es[dd][tx * 4]);                         \
      *(float4*)(bf + 4) = *(const float4*)(&Es[dd][64 + tx * 4]);              \
      _Pragma("unroll")                                                         \
      for (int i = 0; i < 4; ++i)                                               \
        _Pragma("unroll")                                                       \
        for (int j = 0; j < 8; ++j)                                             \
          ACC[i][j] = fmaf(af[i], bf[j], ACC[i][j]);                            \
    }                                                                           \
    __syncthreads();                                                            \
  }

__global__ __launch_bounds__(512) void k_argmin_f32(
    const float* __restrict__ A, const float* __restrict__ E,
    const float* __restrict__ a2, const float* __restrict__ e2,
    float* __restrict__ out_idx, int* __restrict__ idx_ws, int K) {
  __shared__ float As[16][128];
  __shared__ float Es[16][128];
  const int m0 = blockIdx.x * 128;
  const int t = threadIdx.x;
  const int tx = t & 15;
  const int ty = t >> 4;
  float a2l[4];
#pragma unroll
  for (int i = 0; i < 4; ++i) a2l[i] = a2[m0 + ty * 4 + i];
  u64 best[4];
#pragma unroll
  for (int i = 0; i < 4; ++i) best[i] = ~0ULL;
  for (int n0 = 0; n0 < K; n0 += 128) {
    float acc1[4][8], acc2[4][8];
#pragma unroll
    for (int i = 0; i < 4; ++i)
#pragma unroll
      for (int j = 0; j < 8; ++j) { acc1[i][j] = 0.f; acc2[i][j] = 0.f; }
    for (int d0 = 0; d0 < SPLIT_K; d0 += 16) KTILE(d0, acc1)
    for (int d0 = SPLIT_K; d0 < D_DIM; d0 += 16) KTILE(d0, acc2)
    float e2l[8];
#pragma unroll
    for (int j = 0; j < 8; ++j) {
      int cl = (j < 4) ? (tx * 4 + j) : (64 + tx * 4 + (j - 4));
      e2l[j] = e2[n0 + cl];
    }
#pragma unroll
    for (int i = 0; i < 4; ++i) {
#pragma unroll
      for (int j = 0; j < 8; ++j) {
        int cl = (j < 4) ? (tx * 4 + j) : (64 + tx * 4 + (j - 4));
        float S = a2l[i] + e2l[j];
        float m = acc1[i][j] + acc2[i][j];
        float s = fmaf(-2.f, m, S);
        u64 p = ((u64)mono(s) << 32) | (unsigned)(n0 + cl);
        if (p < best[i]) best[i] = p;
      }
    }
  }
#pragma unroll
  for (int m = 1; m < 16; m <<= 1) {
#pragma unroll
    for (int i = 0; i < 4; ++i) {
      u64 o = __shfl_xor(best[i], m, 64);
      if (o < best[i]) best[i] = o;
    }
  }
  if (tx == 0) {
#pragma unroll
    for (int i = 0; i < 4; ++i) {
      int row = m0 + ty * 4 + i;
      int idx = (int)(unsigned)(best[i] & 0xFFFFFFFFULL);
      out_idx[row] = (float)idx;
      idx_ws[row] = idx;
    }
  }
}

__global__ void k_gather(const float* __restrict__ A, const float* __restrict__ E,
                         const int* __restrict__ idx_ws,
                         float* __restrict__ out_z, float* __restrict__ rowsum,
                         int* __restrict__ counts) {
  int b = blockIdx.x;
  int t = threadIdx.x;
  int idx = idx_ws[b];
  const float4* pa = (const float4*)(A + (size_t)b * D_DIM);
  const float4* pe = (const float4*)(E + (size_t)idx * D_DIM);
  float4 a = pa[t];
  float4 e = pe[t];
  float4 z;
  z.x = a.x + (e.x - a.x);
  z.y = a.y + (e.y - a.y);
  z.z = a.z + (e.z - a.z);
  z.w = a.w + (e.w - a.w);
  ((float4*)(out_z + (size_t)b * D_DIM))[t] = z;
  float dx = a.x - e.x, dy = a.y - e.y, dz = a.z - e.z, dw = a.w - e.w;
  float ls = dx * dx + dy * dy + dz * dz + dw * dw;
#pragma unroll
  for (int off = 32; off > 0; off >>= 1) ls += __shfl_down(ls, off, 64);
  __shared__ float wsum[2];
  if ((t & 63) == 0) wsum[t >> 6] = ls;
  __syncthreads();
  if (t == 0) {
    rowsum[b] = wsum[0] + wsum[1];
    atomicAdd(&counts[idx], 1);
  }
}

// ---------------- usage stats + deterministic loss reduction ----------------
__global__ void k_stats(const int* __restrict__ counts, const float* __restrict__ rowsum,
                        float* __restrict__ out_sc, int B, int K) {
  int t = threadIdx.x;
  double ent = 0.0, tot = 0.0, S = 0.0;
  int used = 0;
  for (int k = t; k < K; k += 256) {
    int c = counts[k];
    double u = (double)c / (double)B;
    ent += u * log(u + 1e-10);
    tot += u;
    used += (c > 0) ? 1 : 0;
  }
  for (int b = t; b < B; b += 256) S += (double)rowsum[b];
  __shared__ double se[256];
  __shared__ double st[256];
  __shared__ double ss[256];
  __shared__ int su[256];
  se[t] = ent; st[t] = tot; ss[t] = S; su[t] = used;
  __syncthreads();
  for (int s = 128; s > 0; s >>= 1) {
    if (t < s) { se[t] += se[t + s]; st[t] += st[t + s]; ss[t] += ss[t + s]; su[t] += su[t + s]; }
    __syncthreads();
  }
  if (t == 0) {
    double Sm = ss[0];
    double N = (double)B * (double)D_DIM;
    out_sc[0] = (float)(0.25 * Sm / N);
    out_sc[1] = (float)(Sm / N);
    out_sc[2] = (float)exp(-se[0]);
    out_sc[3] = (float)su[0];
    out_sc[4] = (float)(st[0] / (double)K);
  }
}

extern "C" void kernel_launch(void* const* d_in, const int* in_sizes, int n_in,
                              void* d_out, int out_size, void* d_ws, size_t ws_size,
                              hipStream_t stream) {
  const float* A = (const float*)d_in[0];
  const float* E = (const float*)d_in[1];
  const int B = in_sizes[0] / D_DIM;  // 32768
  const int K = in_sizes[1] / D_DIM;  // 8192

  float* out = (float*)d_out;
  float* out_idx = out;
  float* out_z = out + B;
  float* out_sc = out + B + (size_t)B * D_DIM;

  char* ws = (char*)d_ws;
  size_t off = 0;
  float* a2 = (float*)(ws + off); off += (size_t)B * 4;
  float* e2 = (float*)(ws + off); off += (size_t)K * 4;
  int* counts = (int*)(ws + off); off += (size_t)K * 4;
  float* rowsum = (float*)(ws + off); off += (size_t)B * 4;
  int* idx_ws = (int*)(ws + off); off += (size_t)B * 4;
  int* cand_cnt = (int*)(ws + off); off += (size_t)B * 4;
  unsigned short* cand = (unsigned short*)(ws + off); off += (size_t)B * MAXC * 2;
  unsigned short* Ebf = (unsigned short*)(ws + off); off += (size_t)K * D_DIM * 2;
  float* Eskew = (float*)(ws + off); off += (size_t)K * ESTRIDE * 4;
  const size_t need = off;

  k_init<<<(K + 255) / 256, 256, 0, stream>>>(counts, K);
  k_rowsq<<<(B + 3) / 4, 256, 0, stream>>>(A, a2, B);
  k_rowsq<<<(K + 3) / 4, 256, 0, stream>>>(E, e2, K);

  if (ws_size >= need) {
    int n8 = K * D_DIM / 8;
    k_ebf<<<(n8 + 255) / 256, 256, 0, stream>>>(E, Ebf, n8);
    int n4 = K * D_DIM / 4;
    k_eskew<<<(n4 + 255) / 256, 256, 0, stream>>>(E, Eskew, n4);
    k_screen<<<B / 128, 512, 0, stream>>>(A, Ebf, e2, cand_cnt, cand, K);
    k_rescore<<<B / 4, 256, 0, stream>>>(A, Eskew, a2, e2, cand_cnt, cand,
                                         out_idx, out_z, rowsum, counts, K);
  } else {
    k_argmin_f32<<<B / 128, 512, 0, stream>>>(A, E, a2, e2, out_idx, idx_ws, K);
    k_gather<<<B, 128, 0, stream>>>(A, E, idx_ws, out_z, rowsum, counts);
  }
  k_stats<<<1, 256, 0, stream>>>(counts, rowsum, out_sc, B, K);
}

// Round 7
// 2174.519 us; speedup vs baseline: 15.7419x; 1.9371x over previous
//
#include <hip/hip_runtime.h>
#include <stdint.h>

#define D_DIM 512
#define ESTRIDE 528     // skewed E row stride (floats): 2112B, breaks power-of-2 set mapping
#define SPLIT_K 384     // OpenBLAS sgemm kc (Haswell/ZEN SGEMM_DEFAULT_Q)
#define DELTA 8.0e-4f   // screening window vs FINAL row-min; worst-case need 4.6e-4 (1.7x margin)
                        // r6 lesson: 2e-3 (0.625 sigma) -> ~0.4% rows overflow MAXC -> 16MB/row
                        // straggler scans = 1.9GB FETCH + 2.6ms tail. 8e-4 -> P(overflow) ~1e-8.
#define MAXC 32         // candidate slots per row (expect ~3)

typedef unsigned long long u64;
typedef float f32x4 __attribute__((ext_vector_type(4)));
typedef short s16x8 __attribute__((ext_vector_type(8)));

static __device__ inline unsigned short f2bf(float x) {  // RNE f32->bf16
  unsigned u = __float_as_uint(x);
  u = (u + 0x7FFFu + ((u >> 16) & 1u)) >> 16;
  return (unsigned short)u;
}
static __device__ inline unsigned mono(float f) {  // monotone float->uint
  unsigned u = __float_as_uint(f);
  return (u & 0x80000000u) ? ~u : (u | 0x80000000u);
}
static __device__ inline float unmono(unsigned m) {
  return __uint_as_float((m & 0x80000000u) ? (m & 0x7FFFFFFFu) : ~m);
}

// ---------------- init workspace (histogram only) ----------------
__global__ void k_init(int* __restrict__ counts, int K) {
  int i = blockIdx.x * blockDim.x + threadIdx.x;
  if (i < K) counts[i] = 0;
}

// ---------------- numpy-replicated row sum of squares (validated r2/r3) ----------------
__global__ void k_rowsq(const float* __restrict__ X, float* __restrict__ out, int nrows) {
  int t = threadIdx.x;
  int row = blockIdx.x * 4 + (t >> 6);
  int l = t & 63;
  if (row >= nrows) return;
  int b = l >> 4;
  int L = l & 15;
  const float* p = X + (size_t)row * D_DIM + b * 128 + L;
  float v[8];
#pragma unroll
  for (int j = 0; j < 8; ++j) {
    float x = p[16 * j];
    float sq = x * x;
    asm volatile("" : "+v"(sq));  // numpy squares then sums: no fma contraction
    v[j] = sq;
  }
  float s = ((v[0] + v[1]) + (v[2] + v[3])) + ((v[4] + v[5]) + (v[6] + v[7]));
  s += __shfl_xor(s, 8, 64);
  s += __shfl_xor(s, 4, 64);
  s += __shfl_xor(s, 2, 64);
  s += __shfl_xor(s, 1, 64);
  s += __shfl_xor(s, 16, 64);
  s += __shfl_xor(s, 32, 64);
  if (l == 0) out[row] = s;
}

// ---------------- E f32 -> bf16 ----------------
__global__ void k_ebf(const float* __restrict__ E, unsigned short* __restrict__ Ebf, int n8) {
  int i = blockIdx.x * blockDim.x + threadIdx.x;
  if (i >= n8) return;
  const float4 f0 = ((const float4*)E)[i * 2];
  const float4 f1 = ((const float4*)E)[i * 2 + 1];
  s16x8 o;
  o[0] = (short)f2bf(f0.x); o[1] = (short)f2bf(f0.y);
  o[2] = (short)f2bf(f0.z); o[3] = (short)f2bf(f0.w);
  o[4] = (short)f2bf(f1.x); o[5] = (short)f2bf(f1.y);
  o[6] = (short)f2bf(f1.z); o[7] = (short)f2bf(f1.w);
  ((s16x8*)Ebf)[i] = o;
}

// ---------------- E f32 -> skewed copy (row stride 528 floats) ----------------
__global__ void k_eskew(const float* __restrict__ E, float* __restrict__ Es, int n4) {
  int i = blockIdx.x * blockDim.x + threadIdx.x;  // one float4 per thread
  if (i >= n4) return;
  int row = i >> 7;          // 128 float4 per row
  int c = i & 127;
  float4 v = ((const float4*)(E + (size_t)row * D_DIM))[c];
  ((float4*)(Es + (size_t)row * ESTRIDE))[c] = v;
}

// ---------------- two-phase MFMA bf16 screening (validated r5/r6) ----------------
__global__ __launch_bounds__(512) void k_screen(
    const float* __restrict__ A, const unsigned short* __restrict__ Ebf,
    const float* __restrict__ e2, int* __restrict__ cand_cnt,
    unsigned short* __restrict__ cand, int K) {
  __shared__ unsigned runmin[128];
  __shared__ unsigned cnt[128];
  __shared__ unsigned short list[128 * MAXC];
  __shared__ __align__(16) char Alds[128 * 1024];  // 128 rows x 512 bf16, swizzled

  const int t = threadIdx.x;
  const int m0 = blockIdx.x * 128;

  if (t < 128) { runmin[t] = 0xFFFFFFFFu; cnt[t] = 0; }

  // stage A -> bf16 LDS, 16B chunks, byte XOR-swizzle ((row&7)<<4)
  {
    int row = t >> 2;
    int s4 = t & 3;
    const float* ar = A + (size_t)(m0 + row) * D_DIM;
#pragma unroll
    for (int c = 0; c < 16; ++c) {
      int ch = s4 * 16 + c;  // 16B chunk = 8 bf16
      float4 f0 = *(const float4*)(ar + ch * 8);
      float4 f1 = *(const float4*)(ar + ch * 8 + 4);
      s16x8 o;
      o[0] = (short)f2bf(f0.x); o[1] = (short)f2bf(f0.y);
      o[2] = (short)f2bf(f0.z); o[3] = (short)f2bf(f0.w);
      o[4] = (short)f2bf(f1.x); o[5] = (short)f2bf(f1.y);
      o[6] = (short)f2bf(f1.z); o[7] = (short)f2bf(f1.w);
      int off = ((row * 64 + ch) * 16) ^ ((row & 7) << 4);
      *(s16x8*)(Alds + off) = o;
    }
  }
  __syncthreads();

  const int lane = t & 63;
  const int wid = t >> 6;
  const int wm = wid >> 2;   // 0..1: rows wm*64..+63
  const int wn = wid & 3;    // 0..3: cols wn*32..+31
  const int l15 = lane & 15;
  const int lhi = lane >> 4; // 0..3

  // -------- phase 1: row minima --------
  for (int n0 = 0; n0 < K; n0 += 128) {
    f32x4 acc[4][2];
#pragma unroll
    for (int r = 0; r < 4; ++r)
#pragma unroll
      for (int c = 0; c < 2; ++c) acc[r][c] = (f32x4){0.f, 0.f, 0.f, 0.f};
    const unsigned short* B0 = Ebf + (size_t)(n0 + wn * 32 + l15) * D_DIM + lhi * 8;
    const unsigned short* B1 = B0 + 16 * D_DIM;
#pragma unroll
    for (int dk = 0; dk < 16; ++dk) {
      s16x8 b0 = *(const s16x8*)(B0 + dk * 32);
      s16x8 b1 = *(const s16x8*)(B1 + dk * 32);
      s16x8 af[4];
#pragma unroll
      for (int r = 0; r < 4; ++r) {
        int row = wm * 64 + r * 16 + l15;
        int off = ((row * 64 + dk * 4 + lhi) * 16) ^ ((row & 7) << 4);
        af[r] = *(const s16x8*)(Alds + off);
      }
#pragma unroll
      for (int r = 0; r < 4; ++r) {
        acc[r][0] = __builtin_amdgcn_mfma_f32_16x16x32_bf16(af[r], b0, acc[r][0], 0, 0, 0);
        acc[r][1] = __builtin_amdgcn_mfma_f32_16x16x32_bf16(af[r], b1, acc[r][1], 0, 0, 0);
      }
    }
    float e2c0 = e2[n0 + wn * 32 + l15];
    float e2c1 = e2[n0 + wn * 32 + 16 + l15];
#pragma unroll
    for (int r = 0; r < 4; ++r)
#pragma unroll
      for (int g = 0; g < 4; ++g) {
        float s0 = fmaf(-2.f, acc[r][0][g], e2c0);
        float s1 = fmaf(-2.f, acc[r][1][g], e2c1);
        float mn = fminf(s0, s1);
        mn = fminf(mn, __shfl_xor(mn, 1, 64));
        mn = fminf(mn, __shfl_xor(mn, 2, 64));
        mn = fminf(mn, __shfl_xor(mn, 4, 64));
        mn = fminf(mn, __shfl_xor(mn, 8, 64));
        if (l15 == 0) atomicMin(&runmin[wm * 64 + r * 16 + lhi * 4 + g], mono(mn));
      }
  }
  __syncthreads();

  // -------- phase 2: collect vs final min --------
  float thr[4][4];
#pragma unroll
  for (int r = 0; r < 4; ++r)
#pragma unroll
    for (int g = 0; g < 4; ++g)
      thr[r][g] = unmono(runmin[wm * 64 + r * 16 + lhi * 4 + g]) + DELTA;

  for (int n0 = 0; n0 < K; n0 += 128) {
    f32x4 acc[4][2];
#pragma unroll
    for (int r = 0; r < 4; ++r)
#pragma unroll
      for (int c = 0; c < 2; ++c) acc[r][c] = (f32x4){0.f, 0.f, 0.f, 0.f};
    const unsigned short* B0 = Ebf + (size_t)(n0 + wn * 32 + l15) * D_DIM + lhi * 8;
    const unsigned short* B1 = B0 + 16 * D_DIM;
#pragma unroll
    for (int dk = 0; dk < 16; ++dk) {
      s16x8 b0 = *(const s16x8*)(B0 + dk * 32);
      s16x8 b1 = *(const s16x8*)(B1 + dk * 32);
      s16x8 af[4];
#pragma unroll
      for (int r = 0; r < 4; ++r) {
        int row = wm * 64 + r * 16 + l15;
        int off = ((row * 64 + dk * 4 + lhi) * 16) ^ ((row & 7) << 4);
        af[r] = *(const s16x8*)(Alds + off);
      }
#pragma unroll
      for (int r = 0; r < 4; ++r) {
        acc[r][0] = __builtin_amdgcn_mfma_f32_16x16x32_bf16(af[r], b0, acc[r][0], 0, 0, 0);
        acc[r][1] = __builtin_amdgcn_mfma_f32_16x16x32_bf16(af[r], b1, acc[r][1], 0, 0, 0);
      }
    }
    float e2c0 = e2[n0 + wn * 32 + l15];
    float e2c1 = e2[n0 + wn * 32 + 16 + l15];
#pragma unroll
    for (int r = 0; r < 4; ++r)
#pragma unroll
      for (int g = 0; g < 4; ++g) {
        float s0 = fmaf(-2.f, acc[r][0][g], e2c0);
        float s1 = fmaf(-2.f, acc[r][1][g], e2c1);
        int row = wm * 64 + r * 16 + lhi * 4 + g;
        if (s0 <= thr[r][g]) {
          unsigned p = atomicAdd(&cnt[row], 1u);
          if (p < MAXC) list[row * MAXC + p] = (unsigned short)(n0 + wn * 32 + l15);
        }
        if (s1 <= thr[r][g]) {
          unsigned p = atomicAdd(&cnt[row], 1u);
          if (p < MAXC) list[row * MAXC + p] = (unsigned short)(n0 + wn * 32 + 16 + l15);
        }
      }
  }
  __syncthreads();
  {
    int row = t >> 2;
    unsigned c = cnt[row];
    if ((t & 3) == 0) cand_cnt[m0 + row] = (int)c;
    unsigned cc = c < MAXC ? c : MAXC;
    for (unsigned p = t & 3; p < cc; p += 4)
      cand[(size_t)(m0 + row) * MAXC + p] = list[row * MAXC + p];
  }
}

// ---------------- exact numpy-f32 score (reads skewed E) ----------------
static __device__ inline u64 exact_pack(const float* __restrict__ ar,
                                        const float* __restrict__ er,
                                        float a2r, float e2k, int k) {
  float acc1 = 0.f, acc2 = 0.f;
  for (int d = 0; d < SPLIT_K; d += 4) {
    float4 a = *(const float4*)(ar + d);
    float4 e = *(const float4*)(er + d);
    acc1 = fmaf(a.x, e.x, acc1); acc1 = fmaf(a.y, e.y, acc1);
    acc1 = fmaf(a.z, e.z, acc1); acc1 = fmaf(a.w, e.w, acc1);
  }
  for (int d = SPLIT_K; d < D_DIM; d += 4) {
    float4 a = *(const float4*)(ar + d);
    float4 e = *(const float4*)(er + d);
    acc2 = fmaf(a.x, e.x, acc2); acc2 = fmaf(a.y, e.y, acc2);
    acc2 = fmaf(a.z, e.z, acc2); acc2 = fmaf(a.w, e.w, acc2);
  }
  float M = acc1 + acc2;          // BLAS kc-split merge
  float S = a2r + e2k;            // fl(a2 + e2)
  float s = fmaf(-2.f, M, S);     // fl(S - 2M)
  return ((u64)mono(s) << 32) | (unsigned)k;
}

// ---------------- exact rescore + fused gather/z/loss/histogram ----------------
__global__ __launch_bounds__(256) void k_rescore(
    const float* __restrict__ A, const float* __restrict__ Eskew,
    const float* __restrict__ a2, const float* __restrict__ e2,
    const int* __restrict__ cand_cnt, const unsigned short* __restrict__ cand,
    float* __restrict__ out_idx, float* __restrict__ out_z,
    float* __restrict__ rowsum, int* __restrict__ counts, int K) {
  int lane = threadIdx.x & 63;
  int r = blockIdx.x * 4 + (threadIdx.x >> 6);
  int c = cand_cnt[r];
  const float* ar = A + (size_t)r * D_DIM;
  float a2r = a2[r];
  u64 best = ~0ULL;
  if (c <= MAXC) {
    if (lane < c) {
      int k = cand[(size_t)r * MAXC + lane];
      best = exact_pack(ar, Eskew + (size_t)k * ESTRIDE, a2r, e2[k], k);
    }
  } else {  // overflow net: exact scan of all K (deterministic; P ~ 1e-8)
    for (int k = lane; k < K; k += 64) {
      u64 p = exact_pack(ar, Eskew + (size_t)k * ESTRIDE, a2r, e2[k], k);
      if (p < best) best = p;
    }
  }
#pragma unroll
  for (int m = 1; m < 64; m <<= 1) {
    u64 o = __shfl_xor(best, m, 64);
    if (o < best) best = o;
  }
  int idx = (int)(unsigned)(best & 0xFFFFFFFFULL);

  // fused gather: z, per-row loss partial (each lane: 8 cols)
  const float4* pa = (const float4*)(ar) + lane * 2;
  const float4* pe = (const float4*)(Eskew + (size_t)idx * ESTRIDE) + lane * 2;
  float4* pz = (float4*)(out_z + (size_t)r * D_DIM) + lane * 2;
  float ls = 0.f;
#pragma unroll
  for (int q = 0; q < 2; ++q) {
    float4 a = pa[q];
    float4 e = pe[q];
    float4 z;
    z.x = a.x + (e.x - a.x);  // replicate ref f32 ops exactly
    z.y = a.y + (e.y - a.y);
    z.z = a.z + (e.z - a.z);
    z.w = a.w + (e.w - a.w);
    pz[q] = z;
    float dx = a.x - e.x, dy = a.y - e.y, dz = a.z - e.z, dw = a.w - e.w;
    ls += dx * dx + dy * dy + dz * dz + dw * dw;
  }
#pragma unroll
  for (int m = 1; m < 64; m <<= 1) ls += __shfl_xor(ls, m, 64);
  if (lane == 0) {
    out_idx[r] = (float)idx;
    rowsum[r] = ls;
    atomicAdd(&counts[idx], 1);
  }
}

// ---------------- validated round-3 f32 argmin (ws-size fallback) ----------------
#define KTILE(D0, ACC)                                                          \
  {                                                                             \
    int r = t >> 2;                                                             \
    int c4 = (t & 3) << 2;                                                      \
    float4 va = *(const float4*)(A + (size_t)(m0 + r) * D_DIM + (D0) + c4);     \
    As[c4 + 0][r] = va.x; As[c4 + 1][r] = va.y;                                 \
    As[c4 + 2][r] = va.z; As[c4 + 3][r] = va.w;                                 \
    float4 vb = *(const float4*)(E + (size_t)(n0 + r) * D_DIM + (D0) + c4);     \
    Es[c4 + 0][r] = vb.x; Es[c4 + 1][r] = vb.y;                                 \
    Es[c4 + 2][r] = vb.z; Es[c4 + 3][r] = vb.w;                                 \
    __syncthreads();                                                            \
    _Pragma("unroll")                                                           \
    for (int dd = 0; dd < 16; ++dd) {                                           \
      float af[4], bf[8];                                                       \
      *(float4*)af = *(const float4*)(&As[dd][ty * 4]);                         \
      *(float4*)bf = *(const float4*)(&Es[dd][tx * 4]);                         \
      *(float4*)(bf + 4) = *(const float4*)(&Es[dd][64 + tx * 4]);              \
      _Pragma("unroll")                                                         \
      for (int i = 0; i < 4; ++i)                                               \
        _Pragma("unroll")                                                       \
        for (int j = 0; j < 8; ++j)                                             \
          ACC[i][j] = fmaf(af[i], bf[j], ACC[i][j]);                            \
    }                                                                           \
    __syncthreads();                                                            \
  }

__global__ __launch_bounds__(512) void k_argmin_f32(
    const float* __restrict__ A, const float* __restrict__ E,
    const float* __restrict__ a2, const float* __restrict__ e2,
    float* __restrict__ out_idx, int* __restrict__ idx_ws, int K) {
  __shared__ float As[16][128];
  __shared__ float Es[16][128];
  const int m0 = blockIdx.x * 128;
  const int t = threadIdx.x;
  const int tx = t & 15;
  const int ty = t >> 4;
  float a2l[4];
#pragma unroll
  for (int i = 0; i < 4; ++i) a2l[i] = a2[m0 + ty * 4 + i];
  u64 best[4];
#pragma unroll
  for (int i = 0; i < 4; ++i) best[i] = ~0ULL;
  for (int n0 = 0; n0 < K; n0 += 128) {
    float acc1[4][8], acc2[4][8];
#pragma unroll
    for (int i = 0; i < 4; ++i)
#pragma unroll
      for (int j = 0; j < 8; ++j) { acc1[i][j] = 0.f; acc2[i][j] = 0.f; }
    for (int d0 = 0; d0 < SPLIT_K; d0 += 16) KTILE(d0, acc1)
    for (int d0 = SPLIT_K; d0 < D_DIM; d0 += 16) KTILE(d0, acc2)
    float e2l[8];
#pragma unroll
    for (int j = 0; j < 8; ++j) {
      int cl = (j < 4) ? (tx * 4 + j) : (64 + tx * 4 + (j - 4));
      e2l[j] = e2[n0 + cl];
    }
#pragma unroll
    for (int i = 0; i < 4; ++i) {
#pragma unroll
      for (int j = 0; j < 8; ++j) {
        int cl = (j < 4) ? (tx * 4 + j) : (64 + tx * 4 + (j - 4));
        float S = a2l[i] + e2l[j];
        float m = acc1[i][j] + acc2[i][j];
        float s = fmaf(-2.f, m, S);
        u64 p = ((u64)mono(s) << 32) | (unsigned)(n0 + cl);
        if (p < best[i]) best[i] = p;
      }
    }
  }
#pragma unroll
  for (int m = 1; m < 16; m <<= 1) {
#pragma unroll
    for (int i = 0; i < 4; ++i) {
      u64 o = __shfl_xor(best[i], m, 64);
      if (o < best[i]) best[i] = o;
    }
  }
  if (tx == 0) {
#pragma unroll
    for (int i = 0; i < 4; ++i) {
      int row = m0 + ty * 4 + i;
      int idx = (int)(unsigned)(best[i] & 0xFFFFFFFFULL);
      out_idx[row] = (float)idx;
      idx_ws[row] = idx;
    }
  }
}

__global__ void k_gather(const float* __restrict__ A, const float* __restrict__ E,
                         const int* __restrict__ idx_ws,
                         float* __restrict__ out_z, float* __restrict__ rowsum,
                         int* __restrict__ counts) {
  int b = blockIdx.x;
  int t = threadIdx.x;
  int idx = idx_ws[b];
  const float4* pa = (const float4*)(A + (size_t)b * D_DIM);
  const float4* pe = (const float4*)(E + (size_t)idx * D_DIM);
  float4 a = pa[t];
  float4 e = pe[t];
  float4 z;
  z.x = a.x + (e.x - a.x);
  z.y = a.y + (e.y - a.y);
  z.z = a.z + (e.z - a.z);
  z.w = a.w + (e.w - a.w);
  ((float4*)(out_z + (size_t)b * D_DIM))[t] = z;
  float dx = a.x - e.x, dy = a.y - e.y, dz = a.z - e.z, dw = a.w - e.w;
  float ls = dx * dx + dy * dy + dz * dz + dw * dw;
#pragma unroll
  for (int off = 32; off > 0; off >>= 1) ls += __shfl_down(ls, off, 64);
  __shared__ float wsum[2];
  if ((t & 63) == 0) wsum[t >> 6] = ls;
  __syncthreads();
  if (t == 0) {
    rowsum[b] = wsum[0] + wsum[1];
    atomicAdd(&counts[idx], 1);
  }
}

// ---------------- usage stats + deterministic loss reduction ----------------
__global__ void k_stats(const int* __restrict__ counts, const float* __restrict__ rowsum,
                        float* __restrict__ out_sc, int B, int K) {
  int t = threadIdx.x;
  double ent = 0.0, tot = 0.0, S = 0.0;
  int used = 0;
  for (int k = t; k < K; k += 256) {
    int c = counts[k];
    double u = (double)c / (double)B;
    ent += u * log(u + 1e-10);
    tot += u;
    used += (c > 0) ? 1 : 0;
  }
  for (int b = t; b < B; b += 256) S += (double)rowsum[b];
  __shared__ double se[256];
  __shared__ double st[256];
  __shared__ double ss[256];
  __shared__ int su[256];
  se[t] = ent; st[t] = tot; ss[t] = S; su[t] = used;
  __syncthreads();
  for (int s = 128; s > 0; s >>= 1) {
    if (t < s) { se[t] += se[t + s]; st[t] += st[t + s]; ss[t] += ss[t + s]; su[t] += su[t + s]; }
    __syncthreads();
  }
  if (t == 0) {
    double Sm = ss[0];
    double N = (double)B * (double)D_DIM;
    out_sc[0] = (float)(0.25 * Sm / N);
    out_sc[1] = (float)(Sm / N);
    out_sc[2] = (float)exp(-se[0]);
    out_sc[3] = (float)su[0];
    out_sc[4] = (float)(st[0] / (double)K);
  }
}

extern "C" void kernel_launch(void* const* d_in, const int* in_sizes, int n_in,
                              void* d_out, int out_size, void* d_ws, size_t ws_size,
                              hipStream_t stream) {
  const float* A = (const float*)d_in[0];
  const float* E = (const float*)d_in[1];
  const int B = in_sizes[0] / D_DIM;  // 32768
  const int K = in_sizes[1] / D_DIM;  // 8192

  float* out = (float*)d_out;
  float* out_idx = out;
  float* out_z = out + B;
  float* out_sc = out + B + (size_t)B * D_DIM;

  char* ws = (char*)d_ws;
  size_t off = 0;
  float* a2 = (float*)(ws + off); off += (size_t)B * 4;
  float* e2 = (float*)(ws + off); off += (size_t)K * 4;
  int* counts = (int*)(ws + off); off += (size_t)K * 4;
  float* rowsum = (float*)(ws + off); off += (size_t)B * 4;
  int* idx_ws = (int*)(ws + off); off += (size_t)B * 4;
  int* cand_cnt = (int*)(ws + off); off += (size_t)B * 4;
  unsigned short* cand = (unsigned short*)(ws + off); off += (size_t)B * MAXC * 2;
  unsigned short* Ebf = (unsigned short*)(ws + off); off += (size_t)K * D_DIM * 2;
  float* Eskew = (float*)(ws + off); off += (size_t)K * ESTRIDE * 4;
  const size_t need = off;

  k_init<<<(K + 255) / 256, 256, 0, stream>>>(counts, K);
  k_rowsq<<<(B + 3) / 4, 256, 0, stream>>>(A, a2, B);
  k_rowsq<<<(K + 3) / 4, 256, 0, stream>>>(E, e2, K);

  if (ws_size >= need) {
    int n8 = K * D_DIM / 8;
    k_ebf<<<(n8 + 255) / 256, 256, 0, stream>>>(E, Ebf, n8);
    int n4 = K * D_DIM / 4;
    k_eskew<<<(n4 + 255) / 256, 256, 0, stream>>>(E, Eskew, n4);
    k_screen<<<B / 128, 512, 0, stream>>>(A, Ebf, e2, cand_cnt, cand, K);
    k_rescore<<<B / 4, 256, 0, stream>>>(A, Eskew, a2, e2, cand_cnt, cand,
                                         out_idx, out_z, rowsum, counts, K);
  } else {
    k_argmin_f32<<<B / 128, 512, 0, stream>>>(A, E, a2, e2, out_idx, idx_ws, K);
    k_gather<<<B, 128, 0, stream>>>(A, E, idx_ws, out_z, rowsum, counts);
  }
  k_stats<<<1, 256, 0, stream>>>(counts, rowsum, out_sc, B, K);
}

// Round 8
// 1039.356 us; speedup vs baseline: 32.9348x; 2.0922x over previous
//
#include <hip/hip_runtime.h>
#include <stdint.h>

#define D_DIM 512
#define ESTRIDE 528     // skewed E row stride (floats): 2112B, breaks power-of-2 set mapping
#define SPLIT_K 384     // OpenBLAS sgemm kc (Haswell/ZEN SGEMM_DEFAULT_Q)
#define DELTA 8.0e-4f   // screening window; worst-case need 4.6e-4 (1.7x margin), validated r7
#define MAXC 48         // candidate slots per row; running-min collect expects ~12-18 (r8)

typedef unsigned long long u64;
typedef float f32x4 __attribute__((ext_vector_type(4)));
typedef short s16x8 __attribute__((ext_vector_type(8)));

static __device__ inline unsigned short f2bf(float x) {  // RNE f32->bf16
  unsigned u = __float_as_uint(x);
  u = (u + 0x7FFFu + ((u >> 16) & 1u)) >> 16;
  return (unsigned short)u;
}
static __device__ inline unsigned mono(float f) {  // monotone float->uint
  unsigned u = __float_as_uint(f);
  return (u & 0x80000000u) ? ~u : (u | 0x80000000u);
}
static __device__ inline float unmono(unsigned m) {
  return __uint_as_float((m & 0x80000000u) ? (m & 0x7FFFFFFFu) : ~m);
}

// ---------------- init workspace (histogram only) ----------------
__global__ void k_init(int* __restrict__ counts, int K) {
  int i = blockIdx.x * blockDim.x + threadIdx.x;
  if (i < K) counts[i] = 0;
}

// ---------------- numpy-replicated row sum of squares (validated r2/r3) ----------------
__global__ void k_rowsq(const float* __restrict__ X, float* __restrict__ out, int nrows) {
  int t = threadIdx.x;
  int row = blockIdx.x * 4 + (t >> 6);
  int l = t & 63;
  if (row >= nrows) return;
  int b = l >> 4;
  int L = l & 15;
  const float* p = X + (size_t)row * D_DIM + b * 128 + L;
  float v[8];
#pragma unroll
  for (int j = 0; j < 8; ++j) {
    float x = p[16 * j];
    float sq = x * x;
    asm volatile("" : "+v"(sq));  // numpy squares then sums: no fma contraction
    v[j] = sq;
  }
  float s = ((v[0] + v[1]) + (v[2] + v[3])) + ((v[4] + v[5]) + (v[6] + v[7]));
  s += __shfl_xor(s, 8, 64);
  s += __shfl_xor(s, 4, 64);
  s += __shfl_xor(s, 2, 64);
  s += __shfl_xor(s, 1, 64);
  s += __shfl_xor(s, 16, 64);
  s += __shfl_xor(s, 32, 64);
  if (l == 0) out[row] = s;
}

// ---------------- E f32 -> bf16 ----------------
__global__ void k_ebf(const float* __restrict__ E, unsigned short* __restrict__ Ebf, int n8) {
  int i = blockIdx.x * blockDim.x + threadIdx.x;
  if (i >= n8) return;
  const float4 f0 = ((const float4*)E)[i * 2];
  const float4 f1 = ((const float4*)E)[i * 2 + 1];
  s16x8 o;
  o[0] = (short)f2bf(f0.x); o[1] = (short)f2bf(f0.y);
  o[2] = (short)f2bf(f0.z); o[3] = (short)f2bf(f0.w);
  o[4] = (short)f2bf(f1.x); o[5] = (short)f2bf(f1.y);
  o[6] = (short)f2bf(f1.z); o[7] = (short)f2bf(f1.w);
  ((s16x8*)Ebf)[i] = o;
}

// ---------------- E f32 -> skewed copy (row stride 528 floats) ----------------
__global__ void k_eskew(const float* __restrict__ E, float* __restrict__ Es, int n4) {
  int i = blockIdx.x * blockDim.x + threadIdx.x;  // one float4 per thread
  if (i >= n4) return;
  int row = i >> 7;          // 128 float4 per row
  int c = i & 127;
  float4 v = ((const float4*)(E + (size_t)row * D_DIM))[c];
  ((float4*)(Es + (size_t)row * ESTRIDE))[c] = v;
}

// ---------------- single-pass MFMA bf16 screening ----------------
// Running-min collection is SAFE with tight DELTA: runmin (LDS, monotone u32)
// only decreases and is always >= final row-min, so the numpy winner k*
// (s~(k*) <= final_min + DELTA) passes the collect test at ANY timing.
// Extra loose-threshold collects (~12-18/row) are absorbed by MAXC=48 and
// resolved exactly in k_rescore. cnt > MAXC -> exact full-K scan (same answer).
__global__ __launch_bounds__(512) void k_screen(
    const float* __restrict__ A, const unsigned short* __restrict__ Ebf,
    const float* __restrict__ e2, int* __restrict__ cand_cnt,
    unsigned short* __restrict__ cand, int K) {
  __shared__ unsigned runmin[128];
  __shared__ unsigned cnt[128];
  __shared__ unsigned short list[128 * MAXC];
  __shared__ __align__(16) char Alds[128 * 1024];  // 128 rows x 512 bf16, swizzled

  const int t = threadIdx.x;
  const int m0 = blockIdx.x * 128;

  if (t < 128) { runmin[t] = 0xFFFFFFFFu; cnt[t] = 0; }

  // stage A -> bf16 LDS, 16B chunks, byte XOR-swizzle ((row&7)<<4)
  {
    int row = t >> 2;
    int s4 = t & 3;
    const float* ar = A + (size_t)(m0 + row) * D_DIM;
#pragma unroll
    for (int c = 0; c < 16; ++c) {
      int ch = s4 * 16 + c;  // 16B chunk = 8 bf16
      float4 f0 = *(const float4*)(ar + ch * 8);
      float4 f1 = *(const float4*)(ar + ch * 8 + 4);
      s16x8 o;
      o[0] = (short)f2bf(f0.x); o[1] = (short)f2bf(f0.y);
      o[2] = (short)f2bf(f0.z); o[3] = (short)f2bf(f0.w);
      o[4] = (short)f2bf(f1.x); o[5] = (short)f2bf(f1.y);
      o[6] = (short)f2bf(f1.z); o[7] = (short)f2bf(f1.w);
      int off = ((row * 64 + ch) * 16) ^ ((row & 7) << 4);
      *(s16x8*)(Alds + off) = o;
    }
  }
  __syncthreads();

  const int lane = t & 63;
  const int wid = t >> 6;
  const int wm = wid >> 2;   // 0..1: rows wm*64..+63
  const int wn = wid & 3;    // 0..3: cols wn*32..+31
  const int l15 = lane & 15;
  const int lhi = lane >> 4; // 0..3

  for (int n0 = 0; n0 < K; n0 += 128) {
    f32x4 acc[4][2];
#pragma unroll
    for (int r = 0; r < 4; ++r)
#pragma unroll
      for (int c = 0; c < 2; ++c) acc[r][c] = (f32x4){0.f, 0.f, 0.f, 0.f};
    const unsigned short* B0 = Ebf + (size_t)(n0 + wn * 32 + l15) * D_DIM + lhi * 8;
    const unsigned short* B1 = B0 + 16 * D_DIM;
#pragma unroll
    for (int dk = 0; dk < 16; ++dk) {
      s16x8 b0 = *(const s16x8*)(B0 + dk * 32);
      s16x8 b1 = *(const s16x8*)(B1 + dk * 32);
      s16x8 af[4];
#pragma unroll
      for (int r = 0; r < 4; ++r) {
        int row = wm * 64 + r * 16 + l15;
        int off = ((row * 64 + dk * 4 + lhi) * 16) ^ ((row & 7) << 4);
        af[r] = *(const s16x8*)(Alds + off);
      }
#pragma unroll
      for (int r = 0; r < 4; ++r) {
        acc[r][0] = __builtin_amdgcn_mfma_f32_16x16x32_bf16(af[r], b0, acc[r][0], 0, 0, 0);
        acc[r][1] = __builtin_amdgcn_mfma_f32_16x16x32_bf16(af[r], b1, acc[r][1], 0, 0, 0);
      }
    }
    float e2c0 = e2[n0 + wn * 32 + l15];
    float e2c1 = e2[n0 + wn * 32 + 16 + l15];
#pragma unroll
    for (int r = 0; r < 4; ++r)
#pragma unroll
      for (int g = 0; g < 4; ++g) {
        float s0 = fmaf(-2.f, acc[r][0][g], e2c0);
        float s1 = fmaf(-2.f, acc[r][1][g], e2c1);
        int row = wm * 64 + r * 16 + lhi * 4 + g;
        // update running min (own 32 cols)
        float mn = fminf(s0, s1);
        mn = fminf(mn, __shfl_xor(mn, 1, 64));
        mn = fminf(mn, __shfl_xor(mn, 2, 64));
        mn = fminf(mn, __shfl_xor(mn, 4, 64));
        mn = fminf(mn, __shfl_xor(mn, 8, 64));
        if (l15 == 0) atomicMin(&runmin[row], mono(mn));
        // collect vs current running min (always >= final min => superset safe)
        float thr = unmono(runmin[row]) + DELTA;
        if (s0 <= thr) {
          unsigned p = atomicAdd(&cnt[row], 1u);
          if (p < MAXC) list[row * MAXC + p] = (unsigned short)(n0 + wn * 32 + l15);
        }
        if (s1 <= thr) {
          unsigned p = atomicAdd(&cnt[row], 1u);
          if (p < MAXC) list[row * MAXC + p] = (unsigned short)(n0 + wn * 32 + 16 + l15);
        }
      }
  }
  __syncthreads();
  {
    int row = t >> 2;
    unsigned c = cnt[row];
    if ((t & 3) == 0) cand_cnt[m0 + row] = (int)c;
    unsigned cc = c < MAXC ? c : MAXC;
    for (unsigned p = t & 3; p < cc; p += 4)
      cand[(size_t)(m0 + row) * MAXC + p] = list[row * MAXC + p];
  }
}

// ---------------- exact numpy-f32 score (reads skewed E) ----------------
static __device__ inline u64 exact_pack(const float* __restrict__ ar,
                                        const float* __restrict__ er,
                                        float a2r, float e2k, int k) {
  float acc1 = 0.f, acc2 = 0.f;
  for (int d = 0; d < SPLIT_K; d += 4) {
    float4 a = *(const float4*)(ar + d);
    float4 e = *(const float4*)(er + d);
    acc1 = fmaf(a.x, e.x, acc1); acc1 = fmaf(a.y, e.y, acc1);
    acc1 = fmaf(a.z, e.z, acc1); acc1 = fmaf(a.w, e.w, acc1);
  }
  for (int d = SPLIT_K; d < D_DIM; d += 4) {
    float4 a = *(const float4*)(ar + d);
    float4 e = *(const float4*)(er + d);
    acc2 = fmaf(a.x, e.x, acc2); acc2 = fmaf(a.y, e.y, acc2);
    acc2 = fmaf(a.z, e.z, acc2); acc2 = fmaf(a.w, e.w, acc2);
  }
  float M = acc1 + acc2;          // BLAS kc-split merge
  float S = a2r + e2k;            // fl(a2 + e2)
  float s = fmaf(-2.f, M, S);     // fl(S - 2M)
  return ((u64)mono(s) << 32) | (unsigned)k;
}

// ---------------- exact rescore + fused gather/z/loss/histogram ----------------
__global__ __launch_bounds__(256) void k_rescore(
    const float* __restrict__ A, const float* __restrict__ Eskew,
    const float* __restrict__ a2, const float* __restrict__ e2,
    const int* __restrict__ cand_cnt, const unsigned short* __restrict__ cand,
    float* __restrict__ out_idx, float* __restrict__ out_z,
    float* __restrict__ rowsum, int* __restrict__ counts, int K) {
  int lane = threadIdx.x & 63;
  int r = blockIdx.x * 4 + (threadIdx.x >> 6);
  int c = cand_cnt[r];
  const float* ar = A + (size_t)r * D_DIM;
  float a2r = a2[r];
  u64 best = ~0ULL;
  if (c <= MAXC) {
    if (lane < c) {
      int k = cand[(size_t)r * MAXC + lane];
      best = exact_pack(ar, Eskew + (size_t)k * ESTRIDE, a2r, e2[k], k);
    }
  } else {  // overflow net: exact scan of all K (deterministic answer)
    for (int k = lane; k < K; k += 64) {
      u64 p = exact_pack(ar, Eskew + (size_t)k * ESTRIDE, a2r, e2[k], k);
      if (p < best) best = p;
    }
  }
#pragma unroll
  for (int m = 1; m < 64; m <<= 1) {
    u64 o = __shfl_xor(best, m, 64);
    if (o < best) best = o;
  }
  int idx = (int)(unsigned)(best & 0xFFFFFFFFULL);

  // fused gather: z, per-row loss partial (each lane: 8 cols)
  const float4* pa = (const float4*)(ar) + lane * 2;
  const float4* pe = (const float4*)(Eskew + (size_t)idx * ESTRIDE) + lane * 2;
  float4* pz = (float4*)(out_z + (size_t)r * D_DIM) + lane * 2;
  float ls = 0.f;
#pragma unroll
  for (int q = 0; q < 2; ++q) {
    float4 a = pa[q];
    float4 e = pe[q];
    float4 z;
    z.x = a.x + (e.x - a.x);  // replicate ref f32 ops exactly
    z.y = a.y + (e.y - a.y);
    z.z = a.z + (e.z - a.z);
    z.w = a.w + (e.w - a.w);
    pz[q] = z;
    float dx = a.x - e.x, dy = a.y - e.y, dz = a.z - e.z, dw = a.w - e.w;
    ls += dx * dx + dy * dy + dz * dz + dw * dw;
  }
#pragma unroll
  for (int m = 1; m < 64; m <<= 1) ls += __shfl_xor(ls, m, 64);
  if (lane == 0) {
    out_idx[r] = (float)idx;
    rowsum[r] = ls;
    atomicAdd(&counts[idx], 1);
  }
}

// ---------------- validated round-3 f32 argmin (ws-size fallback) ----------------
#define KTILE(D0, ACC)                                                          \
  {                                                                             \
    int r = t >> 2;                                                             \
    int c4 = (t & 3) << 2;                                                      \
    float4 va = *(const float4*)(A + (size_t)(m0 + r) * D_DIM + (D0) + c4);     \
    As[c4 + 0][r] = va.x; As[c4 + 1][r] = va.y;                                 \
    As[c4 + 2][r] = va.z; As[c4 + 3][r] = va.w;                                 \
    float4 vb = *(const float4*)(E + (size_t)(n0 + r) * D_DIM + (D0) + c4);     \
    Es[c4 + 0][r] = vb.x; Es[c4 + 1][r] = vb.y;                                 \
    Es[c4 + 2][r] = vb.z; Es[c4 + 3][r] = vb.w;                                 \
    __syncthreads();                                                            \
    _Pragma("unroll")                                                           \
    for (int dd = 0; dd < 16; ++dd) {                                           \
      float af[4], bf[8];                                                       \
      *(float4*)af = *(const float4*)(&As[dd][ty * 4]);                         \
      *(float4*)bf = *(const float4*)(&Es[dd][tx * 4]);                         \
      *(float4*)(bf + 4) = *(const float4*)(&Es[dd][64 + tx * 4]);              \
      _Pragma("unroll")                                                         \
      for (int i = 0; i < 4; ++i)                                               \
        _Pragma("unroll")                                                       \
        for (int j = 0; j < 8; ++j)                                             \
          ACC[i][j] = fmaf(af[i], bf[j], ACC[i][j]);                            \
    }                                                                           \
    __syncthreads();                                                            \
  }

__global__ __launch_bounds__(512) void k_argmin_f32(
    const float* __restrict__ A, const float* __restrict__ E,
    const float* __restrict__ a2, const float* __restrict__ e2,
    float* __restrict__ out_idx, int* __restrict__ idx_ws, int K) {
  __shared__ float As[16][128];
  __shared__ float Es[16][128];
  const int m0 = blockIdx.x * 128;
  const int t = threadIdx.x;
  const int tx = t & 15;
  const int ty = t >> 4;
  float a2l[4];
#pragma unroll
  for (int i = 0; i < 4; ++i) a2l[i] = a2[m0 + ty * 4 + i];
  u64 best[4];
#pragma unroll
  for (int i = 0; i < 4; ++i) best[i] = ~0ULL;
  for (int n0 = 0; n0 < K; n0 += 128) {
    float acc1[4][8], acc2[4][8];
#pragma unroll
    for (int i = 0; i < 4; ++i)
#pragma unroll
      for (int j = 0; j < 8; ++j) { acc1[i][j] = 0.f; acc2[i][j] = 0.f; }
    for (int d0 = 0; d0 < SPLIT_K; d0 += 16) KTILE(d0, acc1)
    for (int d0 = SPLIT_K; d0 < D_DIM; d0 += 16) KTILE(d0, acc2)
    float e2l[8];
#pragma unroll
    for (int j = 0; j < 8; ++j) {
      int cl = (j < 4) ? (tx * 4 + j) : (64 + tx * 4 + (j - 4));
      e2l[j] = e2[n0 + cl];
    }
#pragma unroll
    for (int i = 0; i < 4; ++i) {
#pragma unroll
      for (int j = 0; j < 8; ++j) {
        int cl = (j < 4) ? (tx * 4 + j) : (64 + tx * 4 + (j - 4));
        float S = a2l[i] + e2l[j];
        float m = acc1[i][j] + acc2[i][j];
        float s = fmaf(-2.f, m, S);
        u64 p = ((u64)mono(s) << 32) | (unsigned)(n0 + cl);
        if (p < best[i]) best[i] = p;
      }
    }
  }
#pragma unroll
  for (int m = 1; m < 16; m <<= 1) {
#pragma unroll
    for (int i = 0; i < 4; ++i) {
      u64 o = __shfl_xor(best[i], m, 64);
      if (o < best[i]) best[i] = o;
    }
  }
  if (tx == 0) {
#pragma unroll
    for (int i = 0; i < 4; ++i) {
      int row = m0 + ty * 4 + i;
      int idx = (int)(unsigned)(best[i] & 0xFFFFFFFFULL);
      out_idx[row] = (float)idx;
      idx_ws[row] = idx;
    }
  }
}

__global__ void k_gather(const float* __restrict__ A, const float* __restrict__ E,
                         const int* __restrict__ idx_ws,
                         float* __restrict__ out_z, float* __restrict__ rowsum,
                         int* __restrict__ counts) {
  int b = blockIdx.x;
  int t = threadIdx.x;
  int idx = idx_ws[b];
  const float4* pa = (const float4*)(A + (size_t)b * D_DIM);
  const float4* pe = (const float4*)(E + (size_t)idx * D_DIM);
  float4 a = pa[t];
  float4 e = pe[t];
  float4 z;
  z.x = a.x + (e.x - a.x);
  z.y = a.y + (e.y - a.y);
  z.z = a.z + (e.z - a.z);
  z.w = a.w + (e.w - a.w);
  ((float4*)(out_z + (size_t)b * D_DIM))[t] = z;
  float dx = a.x - e.x, dy = a.y - e.y, dz = a.z - e.z, dw = a.w - e.w;
  float ls = dx * dx + dy * dy + dz * dz + dw * dw;
#pragma unroll
  for (int off = 32; off > 0; off >>= 1) ls += __shfl_down(ls, off, 64);
  __shared__ float wsum[2];
  if ((t & 63) == 0) wsum[t >> 6] = ls;
  __syncthreads();
  if (t == 0) {
    rowsum[b] = wsum[0] + wsum[1];
    atomicAdd(&counts[idx], 1);
  }
}

// ---------------- usage stats + deterministic loss reduction ----------------
__global__ void k_stats(const int* __restrict__ counts, const float* __restrict__ rowsum,
                        float* __restrict__ out_sc, int B, int K) {
  int t = threadIdx.x;
  double ent = 0.0, tot = 0.0, S = 0.0;
  int used = 0;
  for (int k = t; k < K; k += 256) {
    int c = counts[k];
    double u = (double)c / (double)B;
    ent += u * log(u + 1e-10);
    tot += u;
    used += (c > 0) ? 1 : 0;
  }
  for (int b = t; b < B; b += 256) S += (double)rowsum[b];
  __shared__ double se[256];
  __shared__ double st[256];
  __shared__ double ss[256];
  __shared__ int su[256];
  se[t] = ent; st[t] = tot; ss[t] = S; su[t] = used;
  __syncthreads();
  for (int s = 128; s > 0; s >>= 1) {
    if (t < s) { se[t] += se[t + s]; st[t] += st[t + s]; ss[t] += ss[t + s]; su[t] += su[t + s]; }
    __syncthreads();
  }
  if (t == 0) {
    double Sm = ss[0];
    double N = (double)B * (double)D_DIM;
    out_sc[0] = (float)(0.25 * Sm / N);
    out_sc[1] = (float)(Sm / N);
    out_sc[2] = (float)exp(-se[0]);
    out_sc[3] = (float)su[0];
    out_sc[4] = (float)(st[0] / (double)K);
  }
}

extern "C" void kernel_launch(void* const* d_in, const int* in_sizes, int n_in,
                              void* d_out, int out_size, void* d_ws, size_t ws_size,
                              hipStream_t stream) {
  const float* A = (const float*)d_in[0];
  const float* E = (const float*)d_in[1];
  const int B = in_sizes[0] / D_DIM;  // 32768
  const int K = in_sizes[1] / D_DIM;  // 8192

  float* out = (float*)d_out;
  float* out_idx = out;
  float* out_z = out + B;
  float* out_sc = out + B + (size_t)B * D_DIM;

  char* ws = (char*)d_ws;
  size_t off = 0;
  float* a2 = (float*)(ws + off); off += (size_t)B * 4;
  float* e2 = (float*)(ws + off); off += (size_t)K * 4;
  int* counts = (int*)(ws + off); off += (size_t)K * 4;
  float* rowsum = (float*)(ws + off); off += (size_t)B * 4;
  int* idx_ws = (int*)(ws + off); off += (size_t)B * 4;
  int* cand_cnt = (int*)(ws + off); off += (size_t)B * 4;
  unsigned short* cand = (unsigned short*)(ws + off); off += (size_t)B * MAXC * 2;
  unsigned short* Ebf = (unsigned short*)(ws + off); off += (size_t)K * D_DIM * 2;
  float* Eskew = (float*)(ws + off); off += (size_t)K * ESTRIDE * 4;
  const size_t need = off;

  k_init<<<(K + 255) / 256, 256, 0, stream>>>(counts, K);
  k_rowsq<<<(B + 3) / 4, 256, 0, stream>>>(A, a2, B);
  k_rowsq<<<(K + 3) / 4, 256, 0, stream>>>(E, e2, K);

  if (ws_size >= need) {
    int n8 = K * D_DIM / 8;
    k_ebf<<<(n8 + 255) / 256, 256, 0, stream>>>(E, Ebf, n8);
    int n4 = K * D_DIM / 4;
    k_eskew<<<(n4 + 255) / 256, 256, 0, stream>>>(E, Eskew, n4);
    k_screen<<<B / 128, 512, 0, stream>>>(A, Ebf, e2, cand_cnt, cand, K);
    k_rescore<<<B / 4, 256, 0, stream>>>(A, Eskew, a2, e2, cand_cnt, cand,
                                         out_idx, out_z, rowsum, counts, K);
  } else {
    k_argmin_f32<<<B / 128, 512, 0, stream>>>(A, E, a2, e2, out_idx, idx_ws, K);
    k_gather<<<B, 128, 0, stream>>>(A, E, idx_ws, out_z, rowsum, counts);
  }
  k_stats<<<1, 256, 0, stream>>>(counts, rowsum, out_sc, B, K);
}

// Round 9
// 910.219 us; speedup vs baseline: 37.6075x; 1.1419x over previous
//
#include <hip/hip_runtime.h>
#include <stdint.h>

#define D_DIM 512
#define EBFS 544        // skewed Ebf row stride (bf16): 1088B = 17 lines, breaks 2^n set mapping
#define ESTRIDE 528     // skewed Eskew row stride (f32): 2112B
#define SPLIT_K 384     // OpenBLAS sgemm kc (Haswell/ZEN SGEMM_DEFAULT_Q)
#define DELTA 8.0e-4f   // screening window; worst-case need 4.6e-4 (1.7x margin), validated r7/r8
#define MAXC 48         // candidate slots per row; running-min collect ~12-18 (validated r8)

typedef unsigned long long u64;
typedef float f32x4 __attribute__((ext_vector_type(4)));
typedef short s16x8 __attribute__((ext_vector_type(8)));

static __device__ inline unsigned short f2bf(float x) {  // RNE f32->bf16
  unsigned u = __float_as_uint(x);
  u = (u + 0x7FFFu + ((u >> 16) & 1u)) >> 16;
  return (unsigned short)u;
}
static __device__ inline unsigned mono(float f) {  // monotone float->uint
  unsigned u = __float_as_uint(f);
  return (u & 0x80000000u) ? ~u : (u | 0x80000000u);
}
static __device__ inline float unmono(unsigned m) {
  return __uint_as_float((m & 0x80000000u) ? (m & 0x7FFFFFFFu) : ~m);
}

// ---------------- init workspace (histogram only) ----------------
__global__ void k_init(int* __restrict__ counts, int K) {
  int i = blockIdx.x * blockDim.x + threadIdx.x;
  if (i < K) counts[i] = 0;
}

// ---------------- numpy-replicated row sum of squares (validated r2/r3) ----------------
__global__ void k_rowsq(const float* __restrict__ X, float* __restrict__ out, int nrows) {
  int t = threadIdx.x;
  int row = blockIdx.x * 4 + (t >> 6);
  int l = t & 63;
  if (row >= nrows) return;
  int b = l >> 4;
  int L = l & 15;
  const float* p = X + (size_t)row * D_DIM + b * 128 + L;
  float v[8];
#pragma unroll
  for (int j = 0; j < 8; ++j) {
    float x = p[16 * j];
    float sq = x * x;
    asm volatile("" : "+v"(sq));  // numpy squares then sums: no fma contraction
    v[j] = sq;
  }
  float s = ((v[0] + v[1]) + (v[2] + v[3])) + ((v[4] + v[5]) + (v[6] + v[7]));
  s += __shfl_xor(s, 8, 64);
  s += __shfl_xor(s, 4, 64);
  s += __shfl_xor(s, 2, 64);
  s += __shfl_xor(s, 1, 64);
  s += __shfl_xor(s, 16, 64);
  s += __shfl_xor(s, 32, 64);
  if (l == 0) out[row] = s;
}

// ---------------- E f32 -> bf16, skewed row stride EBFS ----------------
__global__ void k_ebf(const float* __restrict__ E, unsigned short* __restrict__ Ebf, int n8) {
  int i = blockIdx.x * blockDim.x + threadIdx.x;
  if (i >= n8) return;
  int row = i >> 6;  // 64 chunks of 8 bf16 per row
  int ch = i & 63;
  const float4 f0 = *(const float4*)(E + (size_t)row * D_DIM + ch * 8);
  const float4 f1 = *(const float4*)(E + (size_t)row * D_DIM + ch * 8 + 4);
  s16x8 o;
  o[0] = (short)f2bf(f0.x); o[1] = (short)f2bf(f0.y);
  o[2] = (short)f2bf(f0.z); o[3] = (short)f2bf(f0.w);
  o[4] = (short)f2bf(f1.x); o[5] = (short)f2bf(f1.y);
  o[6] = (short)f2bf(f1.z); o[7] = (short)f2bf(f1.w);
  *(s16x8*)(Ebf + (size_t)row * EBFS + ch * 8) = o;
}

// ---------------- E f32 -> skewed copy (row stride 528 floats) ----------------
__global__ void k_eskew(const float* __restrict__ E, float* __restrict__ Es, int n4) {
  int i = blockIdx.x * blockDim.x + threadIdx.x;  // one float4 per thread
  if (i >= n4) return;
  int row = i >> 7;          // 128 float4 per row
  int c = i & 127;
  float4 v = ((const float4*)(E + (size_t)row * D_DIM))[c];
  ((float4*)(Es + (size_t)row * ESTRIDE))[c] = v;
}

// ---------------- single-pass MFMA bf16 screening (validated r8 logic) ----------------
// r9: full-tile register prefetch of B (32 frags), skewed Ebf, (row&15) LDS swizzle.
__global__ __launch_bounds__(512, 2) void k_screen(
    const float* __restrict__ A, const unsigned short* __restrict__ Ebf,
    const float* __restrict__ e2, int* __restrict__ cand_cnt,
    unsigned short* __restrict__ cand, int K) {
  __shared__ unsigned runmin[128];
  __shared__ unsigned cnt[128];
  __shared__ unsigned short list[128 * MAXC];
  __shared__ __align__(16) char Alds[128 * 1024];  // 128 rows x 512 bf16, swizzled

  const int t = threadIdx.x;
  const int m0 = blockIdx.x * 128;

  if (t < 128) { runmin[t] = 0xFFFFFFFFu; cnt[t] = 0; }

  // stage A -> bf16 LDS, 16B chunks, byte XOR-swizzle ((row&15)<<4)
  {
    int row = t >> 2;
    int s4 = t & 3;
    const float* ar = A + (size_t)(m0 + row) * D_DIM;
#pragma unroll
    for (int c = 0; c < 16; ++c) {
      int ch = s4 * 16 + c;  // 16B chunk = 8 bf16
      float4 f0 = *(const float4*)(ar + ch * 8);
      float4 f1 = *(const float4*)(ar + ch * 8 + 4);
      s16x8 o;
      o[0] = (short)f2bf(f0.x); o[1] = (short)f2bf(f0.y);
      o[2] = (short)f2bf(f0.z); o[3] = (short)f2bf(f0.w);
      o[4] = (short)f2bf(f1.x); o[5] = (short)f2bf(f1.y);
      o[6] = (short)f2bf(f1.z); o[7] = (short)f2bf(f1.w);
      int off = ((row * 64 + ch) * 16) ^ ((row & 15) << 4);
      *(s16x8*)(Alds + off) = o;
    }
  }
  __syncthreads();

  const int lane = t & 63;
  const int wid = t >> 6;
  const int wm = wid >> 2;   // 0..1: rows wm*64..+63
  const int wn = wid & 3;    // 0..3: cols wn*32..+31
  const int l15 = lane & 15;
  const int lhi = lane >> 4; // 0..3

  for (int n0 = 0; n0 < K; n0 += 128) {
    // full-tile register prefetch of B: 32 x 16B (loads issue back-to-back,
    // latency hidden under the MFMA loop; no per-dk load stalls)
    s16x8 bb0[16], bb1[16];
    {
      const unsigned short* B0 = Ebf + (size_t)(n0 + wn * 32 + l15) * EBFS + lhi * 8;
      const unsigned short* B1 = B0 + 16 * EBFS;
#pragma unroll
      for (int dk = 0; dk < 16; ++dk) {
        bb0[dk] = *(const s16x8*)(B0 + dk * 32);
        bb1[dk] = *(const s16x8*)(B1 + dk * 32);
      }
    }
    f32x4 acc[4][2];
#pragma unroll
    for (int r = 0; r < 4; ++r)
#pragma unroll
      for (int c = 0; c < 2; ++c) acc[r][c] = (f32x4){0.f, 0.f, 0.f, 0.f};
#pragma unroll
    for (int dk = 0; dk < 16; ++dk) {
      s16x8 af[4];
#pragma unroll
      for (int r = 0; r < 4; ++r) {
        int row = wm * 64 + r * 16 + l15;
        int off = ((row * 64 + dk * 4 + lhi) * 16) ^ ((row & 15) << 4);
        af[r] = *(const s16x8*)(Alds + off);
      }
#pragma unroll
      for (int r = 0; r < 4; ++r) {
        acc[r][0] = __builtin_amdgcn_mfma_f32_16x16x32_bf16(af[r], bb0[dk], acc[r][0], 0, 0, 0);
        acc[r][1] = __builtin_amdgcn_mfma_f32_16x16x32_bf16(af[r], bb1[dk], acc[r][1], 0, 0, 0);
      }
    }
    float e2c0 = e2[n0 + wn * 32 + l15];
    float e2c1 = e2[n0 + wn * 32 + 16 + l15];
#pragma unroll
    for (int r = 0; r < 4; ++r)
#pragma unroll
      for (int g = 0; g < 4; ++g) {
        float s0 = fmaf(-2.f, acc[r][0][g], e2c0);
        float s1 = fmaf(-2.f, acc[r][1][g], e2c1);
        int row = wm * 64 + r * 16 + lhi * 4 + g;
        // update running min (own 32 cols)
        float mn = fminf(s0, s1);
        mn = fminf(mn, __shfl_xor(mn, 1, 64));
        mn = fminf(mn, __shfl_xor(mn, 2, 64));
        mn = fminf(mn, __shfl_xor(mn, 4, 64));
        mn = fminf(mn, __shfl_xor(mn, 8, 64));
        if (l15 == 0) atomicMin(&runmin[row], mono(mn));
        // collect vs current running min (always >= final min => superset safe)
        float thr = unmono(runmin[row]) + DELTA;
        if (s0 <= thr) {
          unsigned p = atomicAdd(&cnt[row], 1u);
          if (p < MAXC) list[row * MAXC + p] = (unsigned short)(n0 + wn * 32 + l15);
        }
        if (s1 <= thr) {
          unsigned p = atomicAdd(&cnt[row], 1u);
          if (p < MAXC) list[row * MAXC + p] = (unsigned short)(n0 + wn * 32 + 16 + l15);
        }
      }
  }
  __syncthreads();
  {
    int row = t >> 2;
    unsigned c = cnt[row];
    if ((t & 3) == 0) cand_cnt[m0 + row] = (int)c;
    unsigned cc = c < MAXC ? c : MAXC;
    for (unsigned p = t & 3; p < cc; p += 4)
      cand[(size_t)(m0 + row) * MAXC + p] = list[row * MAXC + p];
  }
}

// ---------------- exact numpy-f32 score (reads skewed E) ----------------
static __device__ inline u64 exact_pack(const float* __restrict__ ar,
                                        const float* __restrict__ er,
                                        float a2r, float e2k, int k) {
  float acc1 = 0.f, acc2 = 0.f;
  for (int d = 0; d < SPLIT_K; d += 4) {
    float4 a = *(const float4*)(ar + d);
    float4 e = *(const float4*)(er + d);
    acc1 = fmaf(a.x, e.x, acc1); acc1 = fmaf(a.y, e.y, acc1);
    acc1 = fmaf(a.z, e.z, acc1); acc1 = fmaf(a.w, e.w, acc1);
  }
  for (int d = SPLIT_K; d < D_DIM; d += 4) {
    float4 a = *(const float4*)(ar + d);
    float4 e = *(const float4*)(er + d);
    acc2 = fmaf(a.x, e.x, acc2); acc2 = fmaf(a.y, e.y, acc2);
    acc2 = fmaf(a.z, e.z, acc2); acc2 = fmaf(a.w, e.w, acc2);
  }
  float M = acc1 + acc2;          // BLAS kc-split merge
  float S = a2r + e2k;            // fl(a2 + e2)
  float s = fmaf(-2.f, M, S);     // fl(S - 2M)
  return ((u64)mono(s) << 32) | (unsigned)k;
}

// ---------------- exact rescore + fused gather/z/loss/histogram ----------------
__global__ __launch_bounds__(256) void k_rescore(
    const float* __restrict__ A, const float* __restrict__ Eskew,
    const float* __restrict__ a2, const float* __restrict__ e2,
    const int* __restrict__ cand_cnt, const unsigned short* __restrict__ cand,
    float* __restrict__ out_idx, float* __restrict__ out_z,
    float* __restrict__ rowsum, int* __restrict__ counts, int K) {
  int lane = threadIdx.x & 63;
  int r = blockIdx.x * 4 + (threadIdx.x >> 6);
  int c = cand_cnt[r];
  const float* ar = A + (size_t)r * D_DIM;
  float a2r = a2[r];
  u64 best = ~0ULL;
  if (c <= MAXC) {
    if (lane < c) {
      int k = cand[(size_t)r * MAXC + lane];
      best = exact_pack(ar, Eskew + (size_t)k * ESTRIDE, a2r, e2[k], k);
    }
  } else {  // overflow net: exact scan of all K (deterministic answer)
    for (int k = lane; k < K; k += 64) {
      u64 p = exact_pack(ar, Eskew + (size_t)k * ESTRIDE, a2r, e2[k], k);
      if (p < best) best = p;
    }
  }
#pragma unroll
  for (int m = 1; m < 64; m <<= 1) {
    u64 o = __shfl_xor(best, m, 64);
    if (o < best) best = o;
  }
  int idx = (int)(unsigned)(best & 0xFFFFFFFFULL);

  // fused gather: z, per-row loss partial (each lane: 8 cols)
  const float4* pa = (const float4*)(ar) + lane * 2;
  const float4* pe = (const float4*)(Eskew + (size_t)idx * ESTRIDE) + lane * 2;
  float4* pz = (float4*)(out_z + (size_t)r * D_DIM) + lane * 2;
  float ls = 0.f;
#pragma unroll
  for (int q = 0; q < 2; ++q) {
    float4 a = pa[q];
    float4 e = pe[q];
    float4 z;
    z.x = a.x + (e.x - a.x);  // replicate ref f32 ops exactly
    z.y = a.y + (e.y - a.y);
    z.z = a.z + (e.z - a.z);
    z.w = a.w + (e.w - a.w);
    pz[q] = z;
    float dx = a.x - e.x, dy = a.y - e.y, dz = a.z - e.z, dw = a.w - e.w;
    ls += dx * dx + dy * dy + dz * dz + dw * dw;
  }
#pragma unroll
  for (int m = 1; m < 64; m <<= 1) ls += __shfl_xor(ls, m, 64);
  if (lane == 0) {
    out_idx[r] = (float)idx;
    rowsum[r] = ls;
    atomicAdd(&counts[idx], 1);
  }
}

// ---------------- validated round-3 f32 argmin (ws-size fallback) ----------------
#define KTILE(D0, ACC)                                                          \
  {                                                                             \
    int r = t >> 2;                                                             \
    int c4 = (t & 3) << 2;                                                      \
    float4 va = *(const float4*)(A + (size_t)(m0 + r) * D_DIM + (D0) + c4);     \
    As[c4 + 0][r] = va.x; As[c4 + 1][r] = va.y;                                 \
    As[c4 + 2][r] = va.z; As[c4 + 3][r] = va.w;                                 \
    float4 vb = *(const float4*)(E + (size_t)(n0 + r) * D_DIM + (D0) + c4);     \
    Es[c4 + 0][r] = vb.x; Es[c4 + 1][r] = vb.y;                                 \
    Es[c4 + 2][r] = vb.z; Es[c4 + 3][r] = vb.w;                                 \
    __syncthreads();                                                            \
    _Pragma("unroll")                                                           \
    for (int dd = 0; dd < 16; ++dd) {                                           \
      float af[4], bf[8];                                                       \
      *(float4*)af = *(const float4*)(&As[dd][ty * 4]);                         \
      *(float4*)bf = *(const float4*)(&Es[dd][tx * 4]);                         \
      *(float4*)(bf + 4) = *(const float4*)(&Es[dd][64 + tx * 4]);              \
      _Pragma("unroll")                                                         \
      for (int i = 0; i < 4; ++i)                                               \
        _Pragma("unroll")                                                       \
        for (int j = 0; j < 8; ++j)                                             \
          ACC[i][j] = fmaf(af[i], bf[j], ACC[i][j]);                            \
    }                                                                           \
    __syncthreads();                                                            \
  }

__global__ __launch_bounds__(512) void k_argmin_f32(
    const float* __restrict__ A, const float* __restrict__ E,
    const float* __restrict__ a2, const float* __restrict__ e2,
    float* __restrict__ out_idx, int* __restrict__ idx_ws, int K) {
  __shared__ float As[16][128];
  __shared__ float Es[16][128];
  const int m0 = blockIdx.x * 128;
  const int t = threadIdx.x;
  const int tx = t & 15;
  const int ty = t >> 4;
  float a2l[4];
#pragma unroll
  for (int i = 0; i < 4; ++i) a2l[i] = a2[m0 + ty * 4 + i];
  u64 best[4];
#pragma unroll
  for (int i = 0; i < 4; ++i) best[i] = ~0ULL;
  for (int n0 = 0; n0 < K; n0 += 128) {
    float acc1[4][8], acc2[4][8];
#pragma unroll
    for (int i = 0; i < 4; ++i)
#pragma unroll
      for (int j = 0; j < 8; ++j) { acc1[i][j] = 0.f; acc2[i][j] = 0.f; }
    for (int d0 = 0; d0 < SPLIT_K; d0 += 16) KTILE(d0, acc1)
    for (int d0 = SPLIT_K; d0 < D_DIM; d0 += 16) KTILE(d0, acc2)
    float e2l[8];
#pragma unroll
    for (int j = 0; j < 8; ++j) {
      int cl = (j < 4) ? (tx * 4 + j) : (64 + tx * 4 + (j - 4));
      e2l[j] = e2[n0 + cl];
    }
#pragma unroll
    for (int i = 0; i < 4; ++i) {
#pragma unroll
      for (int j = 0; j < 8; ++j) {
        int cl = (j < 4) ? (tx * 4 + j) : (64 + tx * 4 + (j - 4));
        float S = a2l[i] + e2l[j];
        float m = acc1[i][j] + acc2[i][j];
        float s = fmaf(-2.f, m, S);
        u64 p = ((u64)mono(s) << 32) | (unsigned)(n0 + cl);
        if (p < best[i]) best[i] = p;
      }
    }
  }
#pragma unroll
  for (int m = 1; m < 16; m <<= 1) {
#pragma unroll
    for (int i = 0; i < 4; ++i) {
      u64 o = __shfl_xor(best[i], m, 64);
      if (o < best[i]) best[i] = o;
    }
  }
  if (tx == 0) {
#pragma unroll
    for (int i = 0; i < 4; ++i) {
      int row = m0 + ty * 4 + i;
      int idx = (int)(unsigned)(best[i] & 0xFFFFFFFFULL);
      out_idx[row] = (float)idx;
      idx_ws[row] = idx;
    }
  }
}

__global__ void k_gather(const float* __restrict__ A, const float* __restrict__ E,
                         const int* __restrict__ idx_ws,
                         float* __restrict__ out_z, float* __restrict__ rowsum,
                         int* __restrict__ counts) {
  int b = blockIdx.x;
  int t = threadIdx.x;
  int idx = idx_ws[b];
  const float4* pa = (const float4*)(A + (size_t)b * D_DIM);
  const float4* pe = (const float4*)(E + (size_t)idx * D_DIM);
  float4 a = pa[t];
  float4 e = pe[t];
  float4 z;
  z.x = a.x + (e.x - a.x);
  z.y = a.y + (e.y - a.y);
  z.z = a.z + (e.z - a.z);
  z.w = a.w + (e.w - a.w);
  ((float4*)(out_z + (size_t)b * D_DIM))[t] = z;
  float dx = a.x - e.x, dy = a.y - e.y, dz = a.z - e.z, dw = a.w - e.w;
  float ls = dx * dx + dy * dy + dz * dz + dw * dw;
#pragma unroll
  for (int off = 32; off > 0; off >>= 1) ls += __shfl_down(ls, off, 64);
  __shared__ float wsum[2];
  if ((t & 63) == 0) wsum[t >> 6] = ls;
  __syncthreads();
  if (t == 0) {
    rowsum[b] = wsum[0] + wsum[1];
    atomicAdd(&counts[idx], 1);
  }
}

// ---------------- usage stats + deterministic loss reduction ----------------
__global__ void k_stats(const int* __restrict__ counts, const float* __restrict__ rowsum,
                        float* __restrict__ out_sc, int B, int K) {
  int t = threadIdx.x;
  double ent = 0.0, tot = 0.0, S = 0.0;
  int used = 0;
  for (int k = t; k < K; k += 256) {
    int c = counts[k];
    double u = (double)c / (double)B;
    ent += u * log(u + 1e-10);
    tot += u;
    used += (c > 0) ? 1 : 0;
  }
  for (int b = t; b < B; b += 256) S += (double)rowsum[b];
  __shared__ double se[256];
  __shared__ double st[256];
  __shared__ double ss[256];
  __shared__ int su[256];
  se[t] = ent; st[t] = tot; ss[t] = S; su[t] = used;
  __syncthreads();
  for (int s = 128; s > 0; s >>= 1) {
    if (t < s) { se[t] += se[t + s]; st[t] += st[t + s]; ss[t] += ss[t + s]; su[t] += su[t + s]; }
    __syncthreads();
  }
  if (t == 0) {
    double Sm = ss[0];
    double N = (double)B * (double)D_DIM;
    out_sc[0] = (float)(0.25 * Sm / N);
    out_sc[1] = (float)(Sm / N);
    out_sc[2] = (float)exp(-se[0]);
    out_sc[3] = (float)su[0];
    out_sc[4] = (float)(st[0] / (double)K);
  }
}

extern "C" void kernel_launch(void* const* d_in, const int* in_sizes, int n_in,
                              void* d_out, int out_size, void* d_ws, size_t ws_size,
                              hipStream_t stream) {
  const float* A = (const float*)d_in[0];
  const float* E = (const float*)d_in[1];
  const int B = in_sizes[0] / D_DIM;  // 32768
  const int K = in_sizes[1] / D_DIM;  // 8192

  float* out = (float*)d_out;
  float* out_idx = out;
  float* out_z = out + B;
  float* out_sc = out + B + (size_t)B * D_DIM;

  char* ws = (char*)d_ws;
  size_t off = 0;
  float* a2 = (float*)(ws + off); off += (size_t)B * 4;
  float* e2 = (float*)(ws + off); off += (size_t)K * 4;
  int* counts = (int*)(ws + off); off += (size_t)K * 4;
  float* rowsum = (float*)(ws + off); off += (size_t)B * 4;
  int* idx_ws = (int*)(ws + off); off += (size_t)B * 4;
  int* cand_cnt = (int*)(ws + off); off += (size_t)B * 4;
  unsigned short* cand = (unsigned short*)(ws + off); off += (size_t)B * MAXC * 2;
  unsigned short* Ebf = (unsigned short*)(ws + off); off += (size_t)K * EBFS * 2;
  float* Eskew = (float*)(ws + off); off += (size_t)K * ESTRIDE * 4;
  const size_t need = off;

  k_init<<<(K + 255) / 256, 256, 0, stream>>>(counts, K);
  k_rowsq<<<(B + 3) / 4, 256, 0, stream>>>(A, a2, B);
  k_rowsq<<<(K + 3) / 4, 256, 0, stream>>>(E, e2, K);

  if (ws_size >= need) {
    int n8 = K * D_DIM / 8;
    k_ebf<<<(n8 + 255) / 256, 256, 0, stream>>>(E, Ebf, n8);
    int n4 = K * D_DIM / 4;
    k_eskew<<<(n4 + 255) / 256, 256, 0, stream>>>(E, Eskew, n4);
    k_screen<<<B / 128, 512, 0, stream>>>(A, Ebf, e2, cand_cnt, cand, K);
    k_rescore<<<B / 4, 256, 0, stream>>>(A, Eskew, a2, e2, cand_cnt, cand,
                                         out_idx, out_z, rowsum, counts, K);
  } else {
    k_argmin_f32<<<B / 128, 512, 0, stream>>>(A, E, a2, e2, out_idx, idx_ws, K);
    k_gather<<<B, 128, 0, stream>>>(A, E, idx_ws, out_z, rowsum, counts);
  }
  k_stats<<<1, 256, 0, stream>>>(counts, rowsum, out_sc, B, K);
}

// Round 10
// 870.649 us; speedup vs baseline: 39.3167x; 1.0454x over previous
//
#include <hip/hip_runtime.h>
#include <stdint.h>

#define D_DIM 512
#define EBFS 544        // skewed Ebf row stride (bf16): 1088B = 17 lines, breaks 2^n set mapping
#define ESTRIDE 528     // skewed Eskew row stride (f32): 2112B
#define SPLIT_K 384     // OpenBLAS sgemm kc (Haswell/ZEN SGEMM_DEFAULT_Q)
#define DELTA 8.0e-4f   // screening window; worst-case need 4.6e-4 (1.7x margin), validated r7/r8
#define MAXC 48         // candidate slots per row; running-min collect ~12-18 (validated r8)

typedef unsigned long long u64;
typedef float f32x4 __attribute__((ext_vector_type(4)));
typedef short s16x8 __attribute__((ext_vector_type(8)));

static __device__ inline unsigned short f2bf(float x) {  // RNE f32->bf16
  unsigned u = __float_as_uint(x);
  u = (u + 0x7FFFu + ((u >> 16) & 1u)) >> 16;
  return (unsigned short)u;
}
static __device__ inline unsigned mono(float f) {  // monotone float->uint
  unsigned u = __float_as_uint(f);
  return (u & 0x80000000u) ? ~u : (u | 0x80000000u);
}
static __device__ inline float unmono(unsigned m) {
  return __uint_as_float((m & 0x80000000u) ? (m & 0x7FFFFFFFu) : ~m);
}

// ---------------- init (fallback path only) ----------------
__global__ void k_init(int* __restrict__ counts, int K) {
  int i = blockIdx.x * blockDim.x + threadIdx.x;
  if (i < K) counts[i] = 0;
}

// ---------------- fused prep: counts=0, E->bf16(skewed), E->f32(skewed) ----------------
__global__ void k_prep(const float* __restrict__ E, unsigned short* __restrict__ Ebf,
                       float* __restrict__ Eskew, int* __restrict__ counts, int K) {
  int i = blockIdx.x * blockDim.x + threadIdx.x;  // one 8-float chunk per thread
  if (i < K) counts[i] = 0;
  if (i >= K * 64) return;
  int row = i >> 6;
  int ch = i & 63;
  const float* src = E + (size_t)row * D_DIM + ch * 8;
  float4 f0 = *(const float4*)(src);
  float4 f1 = *(const float4*)(src + 4);
  s16x8 o;
  o[0] = (short)f2bf(f0.x); o[1] = (short)f2bf(f0.y);
  o[2] = (short)f2bf(f0.z); o[3] = (short)f2bf(f0.w);
  o[4] = (short)f2bf(f1.x); o[5] = (short)f2bf(f1.y);
  o[6] = (short)f2bf(f1.z); o[7] = (short)f2bf(f1.w);
  *(s16x8*)(Ebf + (size_t)row * EBFS + ch * 8) = o;
  float* dst = Eskew + (size_t)row * ESTRIDE + ch * 8;
  *(float4*)(dst) = f0;
  *(float4*)(dst + 4) = f1;
}

// ---------------- numpy-replicated row sum of squares (validated r2/r3) ----------------
__global__ void k_rowsq(const float* __restrict__ X, float* __restrict__ out, int nrows) {
  int t = threadIdx.x;
  int row = blockIdx.x * 4 + (t >> 6);
  int l = t & 63;
  if (row >= nrows) return;
  int b = l >> 4;
  int L = l & 15;
  const float* p = X + (size_t)row * D_DIM + b * 128 + L;
  float v[8];
#pragma unroll
  for (int j = 0; j < 8; ++j) {
    float x = p[16 * j];
    float sq = x * x;
    asm volatile("" : "+v"(sq));  // numpy squares then sums: no fma contraction
    v[j] = sq;
  }
  float s = ((v[0] + v[1]) + (v[2] + v[3])) + ((v[4] + v[5]) + (v[6] + v[7]));
  s += __shfl_xor(s, 8, 64);
  s += __shfl_xor(s, 4, 64);
  s += __shfl_xor(s, 2, 64);
  s += __shfl_xor(s, 1, 64);
  s += __shfl_xor(s, 16, 64);
  s += __shfl_xor(s, 32, 64);
  if (l == 0) out[row] = s;
}

// ---------------- single-pass MFMA bf16 screening (validated r8/r9 logic) ----------------
// r10: half-tile-depth software pipeline with NAMED register buffers (loop-carried
// liveness forces real prefetch; static indexing avoids scratch per rule #20).
#define LOADH(BUF, P0, P1, DKB)                                                 \
  _Pragma("unroll") for (int dk = 0; dk < 8; ++dk) {                            \
    BUF[dk]     = *(const s16x8*)((P0) + (DKB + dk) * 32);                      \
    BUF[8 + dk] = *(const s16x8*)((P1) + (DKB + dk) * 32);                      \
  }

#define MFMAH(BUF, DKB)                                                         \
  _Pragma("unroll") for (int dk = 0; dk < 8; ++dk) {                            \
    s16x8 af[4];                                                                \
    _Pragma("unroll") for (int r = 0; r < 4; ++r) {                             \
      int row = wm * 64 + r * 16 + l15;                                         \
      int off = ((row * 64 + (DKB + dk) * 4 + lhi) * 16) ^ ((row & 15) << 4);   \
      af[r] = *(const s16x8*)(Alds + off);                                      \
    }                                                                           \
    _Pragma("unroll") for (int r = 0; r < 4; ++r) {                             \
      acc[r][0] = __builtin_amdgcn_mfma_f32_16x16x32_bf16(af[r], BUF[dk], acc[r][0], 0, 0, 0);      \
      acc[r][1] = __builtin_amdgcn_mfma_f32_16x16x32_bf16(af[r], BUF[8 + dk], acc[r][1], 0, 0, 0);  \
    }                                                                           \
  }

__global__ __launch_bounds__(512, 2) void k_screen(
    const float* __restrict__ A, const unsigned short* __restrict__ Ebf,
    const float* __restrict__ e2, int* __restrict__ cand_cnt,
    unsigned short* __restrict__ cand, int K) {
  __shared__ unsigned runmin[128];
  __shared__ unsigned cnt[128];
  __shared__ unsigned short list[128 * MAXC];
  __shared__ __align__(16) char Alds[128 * 1024];  // 128 rows x 512 bf16, swizzled

  const int t = threadIdx.x;
  const int m0 = blockIdx.x * 128;

  if (t < 128) { runmin[t] = 0xFFFFFFFFu; cnt[t] = 0; }

  // stage A -> bf16 LDS, 16B chunks, byte XOR-swizzle ((row&15)<<4)
  {
    int row = t >> 2;
    int s4 = t & 3;
    const float* ar = A + (size_t)(m0 + row) * D_DIM;
#pragma unroll
    for (int c = 0; c < 16; ++c) {
      int ch = s4 * 16 + c;  // 16B chunk = 8 bf16
      float4 f0 = *(const float4*)(ar + ch * 8);
      float4 f1 = *(const float4*)(ar + ch * 8 + 4);
      s16x8 o;
      o[0] = (short)f2bf(f0.x); o[1] = (short)f2bf(f0.y);
      o[2] = (short)f2bf(f0.z); o[3] = (short)f2bf(f0.w);
      o[4] = (short)f2bf(f1.x); o[5] = (short)f2bf(f1.y);
      o[6] = (short)f2bf(f1.z); o[7] = (short)f2bf(f1.w);
      int off = ((row * 64 + ch) * 16) ^ ((row & 15) << 4);
      *(s16x8*)(Alds + off) = o;
    }
  }
  __syncthreads();

  const int lane = t & 63;
  const int wid = t >> 6;
  const int wm = wid >> 2;   // 0..1: rows wm*64..+63
  const int wn = wid & 3;    // 0..3: cols wn*32..+31
  const int l15 = lane & 15;
  const int lhi = lane >> 4; // 0..3

  const unsigned short* Bbase = Ebf + (size_t)(wn * 32 + l15) * EBFS + lhi * 8;

  s16x8 bufA[16], bufB[16];  // half-tile (8 dk x 2 col-groups) double buffer
  LOADH(bufA, Bbase, Bbase + 16 * EBFS, 0)  // tile 0, half 0

  for (int tile = 0; tile < 64; ++tile) {
    const int n0 = tile * 128;
    const unsigned short* P0 = Bbase + (size_t)n0 * EBFS;
    const unsigned short* P1 = P0 + 16 * EBFS;

    f32x4 acc[4][2];
#pragma unroll
    for (int r = 0; r < 4; ++r)
#pragma unroll
      for (int c = 0; c < 2; ++c) acc[r][c] = (f32x4){0.f, 0.f, 0.f, 0.f};

    LOADH(bufB, P0, P1, 8)        // half 1 of current tile (in flight over MFMAH A)
    MFMAH(bufA, 0)                // consume half 0
    if (tile < 63) {
      const unsigned short* N0 = P0 + (size_t)128 * EBFS;
      LOADH(bufA, N0, N0 + 16 * EBFS, 0)  // half 0 of NEXT tile (in flight over MFMAH B + epilogue)
    }
    MFMAH(bufB, 8)                // consume half 1

    float e2c0 = e2[n0 + wn * 32 + l15];
    float e2c1 = e2[n0 + wn * 32 + 16 + l15];
#pragma unroll
    for (int r = 0; r < 4; ++r)
#pragma unroll
      for (int g = 0; g < 4; ++g) {
        float s0 = fmaf(-2.f, acc[r][0][g], e2c0);
        float s1 = fmaf(-2.f, acc[r][1][g], e2c1);
        int row = wm * 64 + r * 16 + lhi * 4 + g;
        // update running min (own 32 cols)
        float mn = fminf(s0, s1);
        mn = fminf(mn, __shfl_xor(mn, 1, 64));
        mn = fminf(mn, __shfl_xor(mn, 2, 64));
        mn = fminf(mn, __shfl_xor(mn, 4, 64));
        mn = fminf(mn, __shfl_xor(mn, 8, 64));
        if (l15 == 0) atomicMin(&runmin[row], mono(mn));
        // collect vs current running min (always >= final min => superset safe)
        float thr = unmono(runmin[row]) + DELTA;
        if (s0 <= thr) {
          unsigned p = atomicAdd(&cnt[row], 1u);
          if (p < MAXC) list[row * MAXC + p] = (unsigned short)(n0 + wn * 32 + l15);
        }
        if (s1 <= thr) {
          unsigned p = atomicAdd(&cnt[row], 1u);
          if (p < MAXC) list[row * MAXC + p] = (unsigned short)(n0 + wn * 32 + 16 + l15);
        }
      }
  }
  __syncthreads();
  {
    int row = t >> 2;
    unsigned c = cnt[row];
    if ((t & 3) == 0) cand_cnt[m0 + row] = (int)c;
    unsigned cc = c < MAXC ? c : MAXC;
    for (unsigned p = t & 3; p < cc; p += 4)
      cand[(size_t)(m0 + row) * MAXC + p] = list[row * MAXC + p];
  }
}

// ---------------- exact numpy-f32 score (reads skewed E) ----------------
static __device__ inline u64 exact_pack(const float* __restrict__ ar,
                                        const float* __restrict__ er,
                                        float a2r, float e2k, int k) {
  float acc1 = 0.f, acc2 = 0.f;
  for (int d = 0; d < SPLIT_K; d += 4) {
    float4 a = *(const float4*)(ar + d);
    float4 e = *(const float4*)(er + d);
    acc1 = fmaf(a.x, e.x, acc1); acc1 = fmaf(a.y, e.y, acc1);
    acc1 = fmaf(a.z, e.z, acc1); acc1 = fmaf(a.w, e.w, acc1);
  }
  for (int d = SPLIT_K; d < D_DIM; d += 4) {
    float4 a = *(const float4*)(ar + d);
    float4 e = *(const float4*)(er + d);
    acc2 = fmaf(a.x, e.x, acc2); acc2 = fmaf(a.y, e.y, acc2);
    acc2 = fmaf(a.z, e.z, acc2); acc2 = fmaf(a.w, e.w, acc2);
  }
  float M = acc1 + acc2;          // BLAS kc-split merge
  float S = a2r + e2k;            // fl(a2 + e2)
  float s = fmaf(-2.f, M, S);     // fl(S - 2M)
  return ((u64)mono(s) << 32) | (unsigned)k;
}

// ---------------- exact rescore + fused gather/z/loss/histogram ----------------
__global__ __launch_bounds__(256) void k_rescore(
    const float* __restrict__ A, const float* __restrict__ Eskew,
    const float* __restrict__ a2, const float* __restrict__ e2,
    const int* __restrict__ cand_cnt, const unsigned short* __restrict__ cand,
    float* __restrict__ out_idx, float* __restrict__ out_z,
    float* __restrict__ rowsum, int* __restrict__ counts, int K) {
  int lane = threadIdx.x & 63;
  int r = blockIdx.x * 4 + (threadIdx.x >> 6);
  int c = cand_cnt[r];
  const float* ar = A + (size_t)r * D_DIM;
  float a2r = a2[r];
  u64 best = ~0ULL;
  if (c <= MAXC) {
    if (lane < c) {
      int k = cand[(size_t)r * MAXC + lane];
      best = exact_pack(ar, Eskew + (size_t)k * ESTRIDE, a2r, e2[k], k);
    }
  } else {  // overflow net: exact scan of all K (deterministic answer)
    for (int k = lane; k < K; k += 64) {
      u64 p = exact_pack(ar, Eskew + (size_t)k * ESTRIDE, a2r, e2[k], k);
      if (p < best) best = p;
    }
  }
#pragma unroll
  for (int m = 1; m < 64; m <<= 1) {
    u64 o = __shfl_xor(best, m, 64);
    if (o < best) best = o;
  }
  int idx = (int)(unsigned)(best & 0xFFFFFFFFULL);

  // fused gather: z, per-row loss partial (each lane: 8 cols)
  const float4* pa = (const float4*)(ar) + lane * 2;
  const float4* pe = (const float4*)(Eskew + (size_t)idx * ESTRIDE) + lane * 2;
  float4* pz = (float4*)(out_z + (size_t)r * D_DIM) + lane * 2;
  float ls = 0.f;
#pragma unroll
  for (int q = 0; q < 2; ++q) {
    float4 a = pa[q];
    float4 e = pe[q];
    float4 z;
    z.x = a.x + (e.x - a.x);  // replicate ref f32 ops exactly
    z.y = a.y + (e.y - a.y);
    z.z = a.z + (e.z - a.z);
    z.w = a.w + (e.w - a.w);
    pz[q] = z;
    float dx = a.x - e.x, dy = a.y - e.y, dz = a.z - e.z, dw = a.w - e.w;
    ls += dx * dx + dy * dy + dz * dz + dw * dw;
  }
#pragma unroll
  for (int m = 1; m < 64; m <<= 1) ls += __shfl_xor(ls, m, 64);
  if (lane == 0) {
    out_idx[r] = (float)idx;
    rowsum[r] = ls;
    atomicAdd(&counts[idx], 1);
  }
}

// ---------------- validated round-3 f32 argmin (ws-size fallback) ----------------
#define KTILE(D0, ACC)                                                          \
  {                                                                             \
    int r = t >> 2;                                                             \
    int c4 = (t & 3) << 2;                                                      \
    float4 va = *(const float4*)(A + (size_t)(m0 + r) * D_DIM + (D0) + c4);     \
    As[c4 + 0][r] = va.x; As[c4 + 1][r] = va.y;                                 \
    As[c4 + 2][r] = va.z; As[c4 + 3][r] = va.w;                                 \
    float4 vb = *(const float4*)(E + (size_t)(n0 + r) * D_DIM + (D0) + c4);     \
    Es[c4 + 0][r] = vb.x; Es[c4 + 1][r] = vb.y;                                 \
    Es[c4 + 2][r] = vb.z; Es[c4 + 3][r] = vb.w;                                 \
    __syncthreads();                                                            \
    _Pragma("unroll")                                                           \
    for (int dd = 0; dd < 16; ++dd) {                                           \
      float af[4], bf[8];                                                       \
      *(float4*)af = *(const float4*)(&As[dd][ty * 4]);                         \
      *(float4*)bf = *(const float4*)(&Es[dd][tx * 4]);                         \
      *(float4*)(bf + 4) = *(const float4*)(&Es[dd][64 + tx * 4]);              \
      _Pragma("unroll")                                                         \
      for (int i = 0; i < 4; ++i)                                               \
        _Pragma("unroll")                                                       \
        for (int j = 0; j < 8; ++j)                                             \
          ACC[i][j] = fmaf(af[i], bf[j], ACC[i][j]);                            \
    }                                                                           \
    __syncthreads();                                                            \
  }

__global__ __launch_bounds__(512) void k_argmin_f32(
    const float* __restrict__ A, const float* __restrict__ E,
    const float* __restrict__ a2, const float* __restrict__ e2,
    float* __restrict__ out_idx, int* __restrict__ idx_ws, int K) {
  __shared__ float As[16][128];
  __shared__ float Es[16][128];
  const int m0 = blockIdx.x * 128;
  const int t = threadIdx.x;
  const int tx = t & 15;
  const int ty = t >> 4;
  float a2l[4];
#pragma unroll
  for (int i = 0; i < 4; ++i) a2l[i] = a2[m0 + ty * 4 + i];
  u64 best[4];
#pragma unroll
  for (int i = 0; i < 4; ++i) best[i] = ~0ULL;
  for (int n0 = 0; n0 < K; n0 += 128) {
    float acc1[4][8], acc2[4][8];
#pragma unroll
    for (int i = 0; i < 4; ++i)
#pragma unroll
      for (int j = 0; j < 8; ++j) { acc1[i][j] = 0.f; acc2[i][j] = 0.f; }
    for (int d0 = 0; d0 < SPLIT_K; d0 += 16) KTILE(d0, acc1)
    for (int d0 = SPLIT_K; d0 < D_DIM; d0 += 16) KTILE(d0, acc2)
    float e2l[8];
#pragma unroll
    for (int j = 0; j < 8; ++j) {
      int cl = (j < 4) ? (tx * 4 + j) : (64 + tx * 4 + (j - 4));
      e2l[j] = e2[n0 + cl];
    }
#pragma unroll
    for (int i = 0; i < 4; ++i) {
#pragma unroll
      for (int j = 0; j < 8; ++j) {
        int cl = (j < 4) ? (tx * 4 + j) : (64 + tx * 4 + (j - 4));
        float S = a2l[i] + e2l[j];
        float m = acc1[i][j] + acc2[i][j];
        float s = fmaf(-2.f, m, S);
        u64 p = ((u64)mono(s) << 32) | (unsigned)(n0 + cl);
        if (p < best[i]) best[i] = p;
      }
    }
  }
#pragma unroll
  for (int m = 1; m < 16; m <<= 1) {
#pragma unroll
    for (int i = 0; i < 4; ++i) {
      u64 o = __shfl_xor(best[i], m, 64);
      if (o < best[i]) best[i] = o;
    }
  }
  if (tx == 0) {
#pragma unroll
    for (int i = 0; i < 4; ++i) {
      int row = m0 + ty * 4 + i;
      int idx = (int)(unsigned)(best[i] & 0xFFFFFFFFULL);
      out_idx[row] = (float)idx;
      idx_ws[row] = idx;
    }
  }
}

__global__ void k_gather(const float* __restrict__ A, const float* __restrict__ E,
                         const int* __restrict__ idx_ws,
                         float* __restrict__ out_z, float* __restrict__ rowsum,
                         int* __restrict__ counts) {
  int b = blockIdx.x;
  int t = threadIdx.x;
  int idx = idx_ws[b];
  const float4* pa = (const float4*)(A + (size_t)b * D_DIM);
  const float4* pe = (const float4*)(E + (size_t)idx * D_DIM);
  float4 a = pa[t];
  float4 e = pe[t];
  float4 z;
  z.x = a.x + (e.x - a.x);
  z.y = a.y + (e.y - a.y);
  z.z = a.z + (e.z - a.z);
  z.w = a.w + (e.w - a.w);
  ((float4*)(out_z + (size_t)b * D_DIM))[t] = z;
  float dx = a.x - e.x, dy = a.y - e.y, dz = a.z - e.z, dw = a.w - e.w;
  float ls = dx * dx + dy * dy + dz * dz + dw * dw;
#pragma unroll
  for (int off = 32; off > 0; off >>= 1) ls += __shfl_down(ls, off, 64);
  __shared__ float wsum[2];
  if ((t & 63) == 0) wsum[t >> 6] = ls;
  __syncthreads();
  if (t == 0) {
    rowsum[b] = wsum[0] + wsum[1];
    atomicAdd(&counts[idx], 1);
  }
}

// ---------------- usage stats + deterministic loss reduction ----------------
__global__ void k_stats(const int* __restrict__ counts, const float* __restrict__ rowsum,
                        float* __restrict__ out_sc, int B, int K) {
  int t = threadIdx.x;
  double ent = 0.0, tot = 0.0, S = 0.0;
  int used = 0;
  for (int k = t; k < K; k += 256) {
    int c = counts[k];
    double u = (double)c / (double)B;
    ent += u * log(u + 1e-10);
    tot += u;
    used += (c > 0) ? 1 : 0;
  }
  for (int b = t; b < B; b += 256) S += (double)rowsum[b];
  __shared__ double se[256];
  __shared__ double st[256];
  __shared__ double ss[256];
  __shared__ int su[256];
  se[t] = ent; st[t] = tot; ss[t] = S; su[t] = used;
  __syncthreads();
  for (int s = 128; s > 0; s >>= 1) {
    if (t < s) { se[t] += se[t + s]; st[t] += st[t + s]; ss[t] += ss[t + s]; su[t] += su[t + s]; }
    __syncthreads();
  }
  if (t == 0) {
    double Sm = ss[0];
    double N = (double)B * (double)D_DIM;
    out_sc[0] = (float)(0.25 * Sm / N);
    out_sc[1] = (float)(Sm / N);
    out_sc[2] = (float)exp(-se[0]);
    out_sc[3] = (float)su[0];
    out_sc[4] = (float)(st[0] / (double)K);
  }
}

extern "C" void kernel_launch(void* const* d_in, const int* in_sizes, int n_in,
                              void* d_out, int out_size, void* d_ws, size_t ws_size,
                              hipStream_t stream) {
  const float* A = (const float*)d_in[0];
  const float* E = (const float*)d_in[1];
  const int B = in_sizes[0] / D_DIM;  // 32768
  const int K = in_sizes[1] / D_DIM;  // 8192

  float* out = (float*)d_out;
  float* out_idx = out;
  float* out_z = out + B;
  float* out_sc = out + B + (size_t)B * D_DIM;

  char* ws = (char*)d_ws;
  size_t off = 0;
  float* a2 = (float*)(ws + off); off += (size_t)B * 4;
  float* e2 = (float*)(ws + off); off += (size_t)K * 4;
  int* counts = (int*)(ws + off); off += (size_t)K * 4;
  float* rowsum = (float*)(ws + off); off += (size_t)B * 4;
  int* idx_ws = (int*)(ws + off); off += (size_t)B * 4;
  int* cand_cnt = (int*)(ws + off); off += (size_t)B * 4;
  unsigned short* cand = (unsigned short*)(ws + off); off += (size_t)B * MAXC * 2;
  unsigned short* Ebf = (unsigned short*)(ws + off); off += (size_t)K * EBFS * 2;
  float* Eskew = (float*)(ws + off); off += (size_t)K * ESTRIDE * 4;
  const size_t need = off;

  k_rowsq<<<(B + 3) / 4, 256, 0, stream>>>(A, a2, B);
  k_rowsq<<<(K + 3) / 4, 256, 0, stream>>>(E, e2, K);

  if (ws_size >= need) {
    int np = K * 64;
    k_prep<<<(np + 255) / 256, 256, 0, stream>>>(E, Ebf, Eskew, counts, K);
    k_screen<<<B / 128, 512, 0, stream>>>(A, Ebf, e2, cand_cnt, cand, K);
    k_rescore<<<B / 4, 256, 0, stream>>>(A, Eskew, a2, e2, cand_cnt, cand,
                                         out_idx, out_z, rowsum, counts, K);
  } else {
    k_init<<<(K + 255) / 256, 256, 0, stream>>>(counts, K);
    k_argmin_f32<<<B / 128, 512, 0, stream>>>(A, E, a2, e2, out_idx, idx_ws, K);
    k_gather<<<B, 128, 0, stream>>>(A, E, idx_ws, out_z, rowsum, counts);
  }
  k_stats<<<1, 256, 0, stream>>>(counts, rowsum, out_sc, B, K);
}